// Round 1
// baseline (1850.778 us; speedup 1.0000x reference)
//
#include <hip/hip_runtime.h>
#include <math.h>

constexpr int SEQ  = 4096;
constexpr int DIM  = 512;
constexpr int NH   = 8;
constexpr int HDIM = 64;
constexpr int FFD  = 2048;
constexpr int QT   = 4;           // q-rows per attention block

// ---------------- LayerNorm (+affine) ----------------
__global__ void ln_kernel(const float* __restrict__ x, float* __restrict__ out,
                          const float* __restrict__ gammas, const float* __restrict__ betas,
                          int gi) {
    int row = blockIdx.x;
    int t = threadIdx.x;                 // 256 threads
    const float* xr = x + (size_t)row * DIM;
    float v0 = xr[t], v1 = xr[t + 256];
    __shared__ float rs[256], rq[256];
    rs[t] = v0 + v1;
    rq[t] = v0 * v0 + v1 * v1;
    __syncthreads();
    for (int o = 128; o > 0; o >>= 1) {
        if (t < o) { rs[t] += rs[t + o]; rq[t] += rq[t + o]; }
        __syncthreads();
    }
    float mean = rs[0] / DIM;
    float var  = rq[0] / DIM - mean * mean;
    float rstd = rsqrtf(var + 1e-5f);
    float g = gammas[gi], b = betas[gi];
    out[(size_t)row * DIM + t]       = g * ((v0 - mean) * rstd) + b;
    out[(size_t)row * DIM + t + 256] = g * ((v1 - mean) * rstd) + b;
}

// ---------------- generic f32 GEMM: C = A@W (+bias)(+gelu)(+resid) ----------------
// A: MxK row-major, W: KxN row-major. Tile 64x64, BK=16, 256 threads, 4x4 micro.
__global__ __launch_bounds__(256) void gemm_kernel(
    const float* __restrict__ A, const float* __restrict__ W,
    const float* __restrict__ bias, const float* __restrict__ resid,
    float* __restrict__ C, int M, int N, int K, int gelu_flag)
{
    __shared__ float As[16][65];
    __shared__ float Bs[16][64];
    int tid = threadIdx.x;
    int tx = tid & 15, ty = tid >> 4;
    int n0 = blockIdx.x * 64, m0 = blockIdx.y * 64;
    int am = tid >> 2, ak = (tid & 3) * 4;
    int bk = tid >> 4, bn = (tid & 15) * 4;
    float acc[4][4] = {};
    for (int k0 = 0; k0 < K; k0 += 16) {
        float4 av = *(const float4*)(A + (size_t)(m0 + am) * K + k0 + ak);
        float4 bv = *(const float4*)(W + (size_t)(k0 + bk) * N + n0 + bn);
        As[ak + 0][am] = av.x;
        As[ak + 1][am] = av.y;
        As[ak + 2][am] = av.z;
        As[ak + 3][am] = av.w;
        *(float4*)&Bs[bk][bn] = bv;
        __syncthreads();
#pragma unroll
        for (int kk = 0; kk < 16; kk++) {
            float a[4], b[4];
#pragma unroll
            for (int i = 0; i < 4; i++) a[i] = As[kk][ty * 4 + i];
#pragma unroll
            for (int j = 0; j < 4; j++) b[j] = Bs[kk][tx * 4 + j];
#pragma unroll
            for (int i = 0; i < 4; i++)
#pragma unroll
                for (int j = 0; j < 4; j++)
                    acc[i][j] = fmaf(a[i], b[j], acc[i][j]);
        }
        __syncthreads();
    }
#pragma unroll
    for (int i = 0; i < 4; i++) {
        int row = m0 + ty * 4 + i;
#pragma unroll
        for (int j = 0; j < 4; j++) {
            int col = n0 + tx * 4 + j;
            float c = acc[i][j];
            if (bias) c += bias[col];
            if (gelu_flag) c = 0.5f * c * (1.0f + erff(c * 0.70710678118f));
            if (resid) c += resid[(size_t)row * N + col];
            C[(size_t)row * N + col] = c;
        }
    }
}

// ---------------- RoPE (in-place on q and k) ----------------
__global__ void rope_kernel(float* __restrict__ q, float* __restrict__ k) {
    int idx = blockIdx.x * blockDim.x + threadIdx.x;   // SEQ*NH*16
    if (idx >= SEQ * NH * 16) return;
    int i = idx & 15;
    int h = (idx >> 4) & (NH - 1);
    int s = idx >> 7;
    float invf = expf(-(2.0f * i / 32.0f) * logf(10000.0f));
    float freq = (float)s * invf;
    float c = cosf(freq), sn = sinf(freq);
    size_t base = (size_t)s * DIM + h * HDIM + 2 * i;
    float x1 = q[base], x2 = q[base + 1];
    q[base]     = x1 * c - x2 * sn;
    q[base + 1] = x2 * c + x1 * sn;
    x1 = k[base]; x2 = k[base + 1];
    k[base]     = x1 * c - x2 * sn;
    k[base + 1] = x2 * c + x1 * sn;
}

// ---------------- K transpose: k (S, NH*HD) -> kT (NH, HD, S) ----------------
__global__ void transpose_k(const float* __restrict__ k, float* __restrict__ kT) {
    __shared__ float tile[64][65];
    int h = blockIdx.y;
    int s0 = blockIdx.x * 64;
    int t = threadIdx.x;               // 256
    int c = t & 63, r4 = (t >> 6) * 16;
    for (int rr = 0; rr < 16; rr++) {
        int r = r4 + rr;
        tile[r][c] = k[(size_t)(s0 + r) * DIM + h * HDIM + c];
    }
    __syncthreads();
    for (int rr = 0; rr < 16; rr++) {
        int d = r4 + rr;
        kT[((size_t)h * HDIM + d) * SEQ + s0 + c] = tile[c][d];
    }
}

// ---------------- attention: per (head, 4 q-rows) block, full-row softmax ----------------
__global__ __launch_bounds__(256) void attn_kernel(
    const float* __restrict__ q, const float* __restrict__ kT,
    const float* __restrict__ v, const int* __restrict__ mask,
    float* __restrict__ out)
{
    __shared__ float sc[QT][SEQ];           // 64 KB
    __shared__ float qs[QT][HDIM];
    __shared__ float red[256];
    __shared__ float pvred[QT][4][HDIM];
    int t = threadIdx.x;
    int h = blockIdx.x / (SEQ / QT);
    int q0 = (blockIdx.x % (SEQ / QT)) * QT;

    if (t < QT * HDIM) {
        int qi = t / HDIM, d = t % HDIM;
        qs[qi][d] = q[(size_t)(q0 + qi) * DIM + h * HDIM + d];
    }
    __syncthreads();

    // scores
    for (int j = 0; j < SEQ / 256; j++) {
        int sj = j * 256 + t;
        float acc[QT] = {};
        const float* kcol = kT + (size_t)h * HDIM * SEQ + sj;
#pragma unroll 8
        for (int d = 0; d < HDIM; d++) {
            float kv = kcol[(size_t)d * SEQ];
#pragma unroll
            for (int qi = 0; qi < QT; qi++)
                acc[qi] = fmaf(qs[qi][d], kv, acc[qi]);
        }
        int mk = mask[sj];
#pragma unroll
        for (int qi = 0; qi < QT; qi++)
            sc[qi][sj] = mk ? acc[qi] * 0.125f : -1e9f;
    }
    __syncthreads();

    // softmax per row
    float rowsuminv[QT];
    for (int qi = 0; qi < QT; qi++) {
        float mx = -INFINITY;
        for (int j = 0; j < SEQ / 256; j++) mx = fmaxf(mx, sc[qi][j * 256 + t]);
        red[t] = mx; __syncthreads();
        for (int o = 128; o > 0; o >>= 1) {
            if (t < o) red[t] = fmaxf(red[t], red[t + o]);
            __syncthreads();
        }
        mx = red[0]; __syncthreads();
        float sum = 0.0f;
        for (int j = 0; j < SEQ / 256; j++) {
            int sj = j * 256 + t;
            float e = __expf(sc[qi][sj] - mx);
            sc[qi][sj] = e;
            sum += e;
        }
        red[t] = sum; __syncthreads();
        for (int o = 128; o > 0; o >>= 1) {
            if (t < o) red[t] += red[t + o];
            __syncthreads();
        }
        rowsuminv[qi] = 1.0f / red[0];
        __syncthreads();
    }

    // PV
    int d = t & 63, g = t >> 6;
    float pv[QT] = {};
    for (int s = g * (SEQ / 4); s < (g + 1) * (SEQ / 4); s++) {
        float vv = v[(size_t)s * DIM + h * HDIM + d];
#pragma unroll
        for (int qi = 0; qi < QT; qi++) pv[qi] = fmaf(sc[qi][s], vv, pv[qi]);
    }
#pragma unroll
    for (int qi = 0; qi < QT; qi++) pvred[qi][g][d] = pv[qi];
    __syncthreads();
    {
        int qi = t >> 6;          // 256 threads = 4 rows x 64 dims
        int dd = t & 63;
        float o = (pvred[qi][0][dd] + pvred[qi][1][dd] + pvred[qi][2][dd] + pvred[qi][3][dd])
                  * rowsuminv[qi];
        out[(size_t)(q0 + qi) * DIM + h * HDIM + dd] = o;
    }
}

extern "C" void kernel_launch(void* const* d_in, const int* in_sizes, int n_in,
                              void* d_out, int out_size, void* d_ws, size_t ws_size,
                              hipStream_t stream) {
    const float* x      = (const float*)d_in[0];
    const float* gammas = (const float*)d_in[1];
    const float* betas  = (const float*)d_in[2];
    const float* wq     = (const float*)d_in[3];
    const float* wk     = (const float*)d_in[4];
    const float* wv     = (const float*)d_in[5];
    const float* wo     = (const float*)d_in[6];
    const float* bo     = (const float*)d_in[7];
    const float* w1     = (const float*)d_in[8];
    const float* b1     = (const float*)d_in[9];
    const float* w2     = (const float*)d_in[10];
    const float* b2     = (const float*)d_in[11];
    const int*   mask   = (const int*)d_in[12];
    float* out = (float*)d_out;

    const size_t SD = (size_t)SEQ * DIM;   // 2,097,152 floats (8 MB)
    float* ws = (float*)d_ws;
    float* q   = ws;            // [0,1)SD
    float* k   = q + SD;        // [1,2)SD   -- later reused as x2
    float* v   = k + SD;        // [2,3)SD
    float* h1  = v + SD;        // [3,4)SD   -- LN1 out, later attn_out
    float* kT  = h1 + SD;       // [4,5)SD
    float* f1  = v;             // [2,6)SD   -- FFN intermediate (32 MB), after v/h1/kT dead
    float* x2  = k;             // reuse
    float* h2  = q;             // reuse
    // peak ws usage: 6*SD*4 = 48 MB

    // 1. h1 = gamma0*LN(x)+beta0
    ln_kernel<<<SEQ, 256, 0, stream>>>(x, h1, gammas, betas, 0);
    // 2. q,k,v projections
    {
        dim3 grid(DIM / 64, SEQ / 64);
        gemm_kernel<<<grid, 256, 0, stream>>>(h1, wq, nullptr, nullptr, q, SEQ, DIM, DIM, 0);
        gemm_kernel<<<grid, 256, 0, stream>>>(h1, wk, nullptr, nullptr, k, SEQ, DIM, DIM, 0);
        gemm_kernel<<<grid, 256, 0, stream>>>(h1, wv, nullptr, nullptr, v, SEQ, DIM, DIM, 0);
    }
    // 3. RoPE in-place on q,k
    rope_kernel<<<(SEQ * NH * 16) / 256, 256, 0, stream>>>(q, k);
    // 4. kT = transpose(k) per head
    {
        dim3 grid(SEQ / 64, NH);
        transpose_k<<<grid, 256, 0, stream>>>(k, kT);
    }
    // 5. attn_out (into h1)
    attn_kernel<<<NH * (SEQ / QT), 256, 0, stream>>>(q, kT, v, mask, h1);
    // 6. x2 = x + attn_out@wo + bo
    {
        dim3 grid(DIM / 64, SEQ / 64);
        gemm_kernel<<<grid, 256, 0, stream>>>(h1, wo, bo, x, x2, SEQ, DIM, DIM, 0);
    }
    // 7. h2 = gamma1*LN(x2)+beta1
    ln_kernel<<<SEQ, 256, 0, stream>>>(x2, h2, gammas, betas, 1);
    // 8. f1 = gelu(h2@w1 + b1)
    {
        dim3 grid(FFD / 64, SEQ / 64);
        gemm_kernel<<<grid, 256, 0, stream>>>(h2, w1, b1, nullptr, f1, SEQ, FFD, DIM, 1);
    }
    // 9. out = x2 + f1@w2 + b2
    {
        dim3 grid(DIM / 64, SEQ / 64);
        gemm_kernel<<<grid, 256, 0, stream>>>(f1, w2, b2, x2, out, SEQ, DIM, FFD, 0);
    }
}

// Round 2
// 610.103 us; speedup vs baseline: 3.0336x; 3.0336x over previous
//
#include <hip/hip_runtime.h>
#include <math.h>

constexpr int SEQ  = 4096;
constexpr int DIM  = 512;
constexpr int NH   = 8;
constexpr int HDIM = 64;
constexpr int FFD  = 2048;

typedef __attribute__((ext_vector_type(8))) short bf16x8;
typedef __attribute__((ext_vector_type(4))) float f32x4;
typedef __attribute__((ext_vector_type(8))) unsigned short u16x8;

static __device__ __forceinline__ unsigned short f2bf(float x) {
    union { float f; unsigned int u; } v; v.f = x;
    unsigned int r = v.u + 0x7fff + ((v.u >> 16) & 1);
    return (unsigned short)(r >> 16);
}

// ---------------- LayerNorm (+affine) ----------------
__global__ void ln_kernel(const float* __restrict__ x, float* __restrict__ out,
                          const float* __restrict__ gammas, const float* __restrict__ betas,
                          int gi) {
    int row = blockIdx.x;
    int t = threadIdx.x;                 // 256 threads
    const float* xr = x + (size_t)row * DIM;
    float v0 = xr[t], v1 = xr[t + 256];
    __shared__ float rs[256], rq[256];
    rs[t] = v0 + v1;
    rq[t] = v0 * v0 + v1 * v1;
    __syncthreads();
    for (int o = 128; o > 0; o >>= 1) {
        if (t < o) { rs[t] += rs[t + o]; rq[t] += rq[t + o]; }
        __syncthreads();
    }
    float mean = rs[0] / DIM;
    float var  = rq[0] / DIM - mean * mean;
    float rstd = rsqrtf(var + 1e-5f);
    float g = gammas[gi], b = betas[gi];
    out[(size_t)row * DIM + t]       = g * ((v0 - mean) * rstd) + b;
    out[(size_t)row * DIM + t + 256] = g * ((v1 - mean) * rstd) + b;
}

// ---------------- generic f32 GEMM: C = A@W (+bias)(+gelu)(+resid) ----------------
__global__ __launch_bounds__(256) void gemm_kernel(
    const float* __restrict__ A, const float* __restrict__ W,
    const float* __restrict__ bias, const float* __restrict__ resid,
    float* __restrict__ C, int M, int N, int K, int gelu_flag)
{
    __shared__ float As[16][65];
    __shared__ float Bs[16][64];
    int tid = threadIdx.x;
    int tx = tid & 15, ty = tid >> 4;
    int n0 = blockIdx.x * 64, m0 = blockIdx.y * 64;
    int am = tid >> 2, ak = (tid & 3) * 4;
    int bk = tid >> 4, bn = (tid & 15) * 4;
    float acc[4][4] = {};
    for (int k0 = 0; k0 < K; k0 += 16) {
        float4 av = *(const float4*)(A + (size_t)(m0 + am) * K + k0 + ak);
        float4 bv = *(const float4*)(W + (size_t)(k0 + bk) * N + n0 + bn);
        As[ak + 0][am] = av.x;
        As[ak + 1][am] = av.y;
        As[ak + 2][am] = av.z;
        As[ak + 3][am] = av.w;
        *(float4*)&Bs[bk][bn] = bv;
        __syncthreads();
#pragma unroll
        for (int kk = 0; kk < 16; kk++) {
            float a[4], b[4];
#pragma unroll
            for (int i = 0; i < 4; i++) a[i] = As[kk][ty * 4 + i];
#pragma unroll
            for (int j = 0; j < 4; j++) b[j] = Bs[kk][tx * 4 + j];
#pragma unroll
            for (int i = 0; i < 4; i++)
#pragma unroll
                for (int j = 0; j < 4; j++)
                    acc[i][j] = fmaf(a[i], b[j], acc[i][j]);
        }
        __syncthreads();
    }
#pragma unroll
    for (int i = 0; i < 4; i++) {
        int row = m0 + ty * 4 + i;
#pragma unroll
        for (int j = 0; j < 4; j++) {
            int col = n0 + tx * 4 + j;
            float c = acc[i][j];
            if (bias) c += bias[col];
            if (gelu_flag) c = 0.5f * c * (1.0f + erff(c * 0.70710678118f));
            if (resid) c += resid[(size_t)row * N + col];
            C[(size_t)row * N + col] = c;
        }
    }
}

// ---------------- RoPE (in-place on q and k) ----------------
__global__ void rope_kernel(float* __restrict__ q, float* __restrict__ k) {
    int idx = blockIdx.x * blockDim.x + threadIdx.x;   // SEQ*NH*16
    if (idx >= SEQ * NH * 16) return;
    int i = idx & 15;
    int h = (idx >> 4) & (NH - 1);
    int s = idx >> 7;
    float invf = expf(-(2.0f * i / 32.0f) * logf(10000.0f));
    float freq = (float)s * invf;
    float c = cosf(freq), sn = sinf(freq);
    size_t base = (size_t)s * DIM + h * HDIM + 2 * i;
    float x1 = q[base], x2 = q[base + 1];
    q[base]     = x1 * c - x2 * sn;
    q[base + 1] = x2 * c + x1 * sn;
    x1 = k[base]; x2 = k[base + 1];
    k[base]     = x1 * c - x2 * sn;
    k[base + 1] = x2 * c + x1 * sn;
}

// ---------------- transpose per head: src (S, NH*HD) -> dst (NH, HD, S) ----------------
__global__ void transpose_hd(const float* __restrict__ src, float* __restrict__ dst) {
    __shared__ float tile[64][65];
    int h = blockIdx.y;
    int s0 = blockIdx.x * 64;
    int t = threadIdx.x;               // 256
    int c = t & 63, r4 = (t >> 6) * 16;
    for (int rr = 0; rr < 16; rr++) {
        int r = r4 + rr;
        tile[r][c] = src[(size_t)(s0 + r) * DIM + h * HDIM + c];
    }
    __syncthreads();
    for (int rr = 0; rr < 16; rr++) {
        int d = r4 + rr;
        dst[((size_t)h * HDIM + d) * SEQ + s0 + c] = tile[c][d];
    }
}

// ---------------- flash attention, bf16 MFMA ----------------
// grid (NH, SEQ/64), 256 threads = 4 waves, 16 q-rows per wave.
// mfma_f32_16x16x32_bf16 layouts (verified, learn_hip m89/m97):
//   A frag (8 bf16): lane l -> A[l&15][(l>>4)*8 + j]   (k contiguous)
//   B frag (8 bf16): lane l -> B[(l>>4)*8 + j][l&15]
//   C/D    (4 f32) : lane l, reg r -> D[(l>>4)*4 + r][l&15]
__global__ __launch_bounds__(256) void fattn_kernel(
    const float* __restrict__ q, const float* __restrict__ k,
    const float* __restrict__ vT, const int* __restrict__ mask,
    float* __restrict__ out)
{
    __shared__ __align__(16) unsigned short q_s[64 * 64];        // [qrow][d]
    __shared__ __align__(16) unsigned short k_s[64 * 64];        // [key][d], swizzled
    __shared__ __align__(16) unsigned short vt_s[64 * 64];       // [d][key], swizzled
    __shared__ __align__(16) unsigned short p_s[4][16 * 64];     // per-wave [q][key], swizzled

    const int t = threadIdx.x;
    const int lane = t & 63;
    const int w = t >> 6;
    const int h = blockIdx.x;
    const int q0 = blockIdx.y * 64;

    // ---- stage Q block (f32 -> bf16), unswizzled ----
    {
        int row = t >> 2, c0 = (t & 3) * 16;
        const float* src = q + (size_t)(q0 + row) * DIM + h * HDIM + c0;
        float4 f0 = *(const float4*)(src);
        float4 f1 = *(const float4*)(src + 4);
        float4 f2 = *(const float4*)(src + 8);
        float4 f3 = *(const float4*)(src + 12);
        u16x8 a, b;
        a[0]=f2bf(f0.x); a[1]=f2bf(f0.y); a[2]=f2bf(f0.z); a[3]=f2bf(f0.w);
        a[4]=f2bf(f1.x); a[5]=f2bf(f1.y); a[6]=f2bf(f1.z); a[7]=f2bf(f1.w);
        b[0]=f2bf(f2.x); b[1]=f2bf(f2.y); b[2]=f2bf(f2.z); b[3]=f2bf(f2.w);
        b[4]=f2bf(f3.x); b[5]=f2bf(f3.y); b[6]=f2bf(f3.z); b[7]=f2bf(f3.w);
        *(u16x8*)((char*)q_s + row * 128 + c0 * 2)      = a;
        *(u16x8*)((char*)q_s + row * 128 + c0 * 2 + 16) = b;
    }
    __syncthreads();

    // Q fragments (persist in registers): rows w*16+(l&15), d = (l>>4)*8+j (+32)
    bf16x8 qf0 = *(bf16x8*)((char*)q_s + (w * 16 + (lane & 15)) * 128 + (lane >> 4) * 16);
    bf16x8 qf1 = *(bf16x8*)((char*)q_s + (w * 16 + (lane & 15)) * 128 + (lane >> 4) * 16 + 64);

    f32x4 O[4];
    float mrun[4], lrun[4];
#pragma unroll
    for (int dt = 0; dt < 4; dt++) O[dt] = (f32x4){0.f, 0.f, 0.f, 0.f};
#pragma unroll
    for (int r = 0; r < 4; r++) { mrun[r] = -INFINITY; lrun[r] = 0.f; }

    char* pbase = (char*)p_s[w];
    const int prow = lane & 15;
    const int psw  = (prow & 7) << 4;

    for (int kb = 0; kb < SEQ; kb += 64) {
        // ---- stage K tile [key][d] and V^T tile [d][key] (bf16, swizzled) ----
        {
            int row = t >> 2, c0 = (t & 3) * 16;
            int sw = (row & 7) << 4;
            {
                const float* src = k + (size_t)(kb + row) * DIM + h * HDIM + c0;
                float4 f0 = *(const float4*)(src);
                float4 f1 = *(const float4*)(src + 4);
                float4 f2 = *(const float4*)(src + 8);
                float4 f3 = *(const float4*)(src + 12);
                u16x8 a, b;
                a[0]=f2bf(f0.x); a[1]=f2bf(f0.y); a[2]=f2bf(f0.z); a[3]=f2bf(f0.w);
                a[4]=f2bf(f1.x); a[5]=f2bf(f1.y); a[6]=f2bf(f1.z); a[7]=f2bf(f1.w);
                b[0]=f2bf(f2.x); b[1]=f2bf(f2.y); b[2]=f2bf(f2.z); b[3]=f2bf(f2.w);
                b[4]=f2bf(f3.x); b[5]=f2bf(f3.y); b[6]=f2bf(f3.z); b[7]=f2bf(f3.w);
                char* base = (char*)k_s + row * 128;
                *(u16x8*)(base + ((c0 * 2)      ^ sw)) = a;
                *(u16x8*)(base + ((c0 * 2 + 16) ^ sw)) = b;
            }
            {
                const float* src = vT + ((size_t)h * HDIM + row) * SEQ + kb + c0;
                float4 f0 = *(const float4*)(src);
                float4 f1 = *(const float4*)(src + 4);
                float4 f2 = *(const float4*)(src + 8);
                float4 f3 = *(const float4*)(src + 12);
                u16x8 a, b;
                a[0]=f2bf(f0.x); a[1]=f2bf(f0.y); a[2]=f2bf(f0.z); a[3]=f2bf(f0.w);
                a[4]=f2bf(f1.x); a[5]=f2bf(f1.y); a[6]=f2bf(f1.z); a[7]=f2bf(f1.w);
                b[0]=f2bf(f2.x); b[1]=f2bf(f2.y); b[2]=f2bf(f2.z); b[3]=f2bf(f2.w);
                b[4]=f2bf(f3.x); b[5]=f2bf(f3.y); b[6]=f2bf(f3.z); b[7]=f2bf(f3.w);
                char* base = (char*)vt_s + row * 128;
                *(u16x8*)(base + ((c0 * 2)      ^ sw)) = a;
                *(u16x8*)(base + ((c0 * 2 + 16) ^ sw)) = b;
            }
        }
        __syncthreads();

        // ---- QK^T: S[q][key], 4 key-tiles x (2 MFMAs over d) ----
        f32x4 sacc[4];
#pragma unroll
        for (int kt = 0; kt < 4; kt++) {
            sacc[kt] = (f32x4){0.f, 0.f, 0.f, 0.f};
            int key = kt * 16 + (lane & 15);
            int ksw = (key & 7) << 4;
            char* kbase = (char*)k_s + key * 128;
            bf16x8 b0 = *(bf16x8*)(kbase + (((lane >> 4) * 16)      ^ ksw));
            bf16x8 b1 = *(bf16x8*)(kbase + (((lane >> 4) * 16 + 64) ^ ksw));
            sacc[kt] = __builtin_amdgcn_mfma_f32_16x16x32_bf16(qf0, b0, sacc[kt], 0, 0, 0);
            sacc[kt] = __builtin_amdgcn_mfma_f32_16x16x32_bf16(qf1, b1, sacc[kt], 0, 0, 0);
        }

        // ---- mask + scale ----
#pragma unroll
        for (int kt = 0; kt < 4; kt++) {
            int mk = mask[kb + kt * 16 + (lane & 15)];
            float sc = mk ? 0.125f : 0.0f;
            float ad = mk ? 0.0f : -1e9f;
#pragma unroll
            for (int r = 0; r < 4; r++) sacc[kt][r] = sacc[kt][r] * sc + ad;
        }

        // ---- online softmax (row = (l>>4)*4 + r lives across 16 lanes) ----
        float mnew[4], alpha[4];
#pragma unroll
        for (int r = 0; r < 4; r++) {
            float tm = fmaxf(fmaxf(sacc[0][r], sacc[1][r]), fmaxf(sacc[2][r], sacc[3][r]));
#pragma unroll
            for (int off = 1; off < 16; off <<= 1)
                tm = fmaxf(tm, __shfl_xor(tm, off, 64));
            mnew[r] = fmaxf(mrun[r], tm);
            alpha[r] = __expf(mrun[r] - mnew[r]);
            mrun[r] = mnew[r];
        }
        float rsum[4] = {0.f, 0.f, 0.f, 0.f};
#pragma unroll
        for (int kt = 0; kt < 4; kt++)
#pragma unroll
            for (int r = 0; r < 4; r++) {
                float p = __expf(sacc[kt][r] - mnew[r]);
                sacc[kt][r] = p;
                rsum[r] += p;
            }
#pragma unroll
        for (int r = 0; r < 4; r++) {
            float s = rsum[r];
#pragma unroll
            for (int off = 1; off < 16; off <<= 1)
                s += __shfl_xor(s, off, 64);
            lrun[r] = lrun[r] * alpha[r] + s;
        }
#pragma unroll
        for (int dt = 0; dt < 4; dt++)
#pragma unroll
            for (int r = 0; r < 4; r++) O[dt][r] *= alpha[r];

        // ---- P -> per-wave LDS (bf16, swizzled), D-layout -> A-layout ----
#pragma unroll
        for (int kt = 0; kt < 4; kt++)
#pragma unroll
            for (int r = 0; r < 4; r++) {
                int row = (lane >> 4) * 4 + r;
                int col = kt * 16 + (lane & 15);
                *(unsigned short*)(pbase + ((row * 128) + ((col * 2) ^ ((row & 7) << 4))))
                    = f2bf(sacc[kt][r]);
            }

        // ---- PV: O[q][d] += P[q][key] @ V[key][d] ----
#pragma unroll
        for (int half = 0; half < 2; half++) {
            bf16x8 pa = *(bf16x8*)(pbase + prow * 128 +
                                   (((lane >> 4) * 16 + half * 64) ^ psw));
#pragma unroll
            for (int dt = 0; dt < 4; dt++) {
                int d = dt * 16 + (lane & 15);
                bf16x8 vb = *(bf16x8*)((char*)vt_s + d * 128 +
                                       (((lane >> 4) * 16 + half * 64) ^ ((d & 7) << 4)));
                O[dt] = __builtin_amdgcn_mfma_f32_16x16x32_bf16(pa, vb, O[dt], 0, 0, 0);
            }
        }
        __syncthreads();
    }

    // ---- epilogue ----
#pragma unroll
    for (int dt = 0; dt < 4; dt++)
#pragma unroll
        for (int r = 0; r < 4; r++) {
            int row = q0 + w * 16 + (lane >> 4) * 4 + r;
            int col = h * HDIM + dt * 16 + (lane & 15);
            out[(size_t)row * DIM + col] = O[dt][r] / lrun[r];
        }
}

extern "C" void kernel_launch(void* const* d_in, const int* in_sizes, int n_in,
                              void* d_out, int out_size, void* d_ws, size_t ws_size,
                              hipStream_t stream) {
    const float* x      = (const float*)d_in[0];
    const float* gammas = (const float*)d_in[1];
    const float* betas  = (const float*)d_in[2];
    const float* wq     = (const float*)d_in[3];
    const float* wk     = (const float*)d_in[4];
    const float* wv     = (const float*)d_in[5];
    const float* wo     = (const float*)d_in[6];
    const float* bo     = (const float*)d_in[7];
    const float* w1     = (const float*)d_in[8];
    const float* b1     = (const float*)d_in[9];
    const float* w2     = (const float*)d_in[10];
    const float* b2     = (const float*)d_in[11];
    const int*   mask   = (const int*)d_in[12];
    float* out = (float*)d_out;

    const size_t SD = (size_t)SEQ * DIM;   // 8 MB
    float* ws = (float*)d_ws;
    float* q   = ws;            // slot 0
    float* k   = q + SD;        // slot 1  (later x2)
    float* v   = k + SD;        // slot 2
    float* h1  = v + SD;        // slot 3  (LN1 out, later attn out)
    float* vT  = h1 + SD;       // slot 4
    float* f1  = v;             // slots 2..5 (FFN intermediate, 32 MB)
    float* x2  = k;
    float* h2  = q;

    // 1. h1 = gamma0*LN(x)+beta0
    ln_kernel<<<SEQ, 256, 0, stream>>>(x, h1, gammas, betas, 0);
    // 2. q,k,v projections
    {
        dim3 grid(DIM / 64, SEQ / 64);
        gemm_kernel<<<grid, 256, 0, stream>>>(h1, wq, nullptr, nullptr, q, SEQ, DIM, DIM, 0);
        gemm_kernel<<<grid, 256, 0, stream>>>(h1, wk, nullptr, nullptr, k, SEQ, DIM, DIM, 0);
        gemm_kernel<<<grid, 256, 0, stream>>>(h1, wv, nullptr, nullptr, v, SEQ, DIM, DIM, 0);
    }
    // 3. RoPE in-place on q,k
    rope_kernel<<<(SEQ * NH * 16) / 256, 256, 0, stream>>>(q, k);
    // 4. vT = per-head transpose of v
    {
        dim3 grid(SEQ / 64, NH);
        transpose_hd<<<grid, 256, 0, stream>>>(v, vT);
    }
    // 5. attention (into h1)
    {
        dim3 grid(NH, SEQ / 64);
        fattn_kernel<<<grid, 256, 0, stream>>>(q, k, vT, mask, h1);
    }
    // 6. x2 = x + attn_out@wo + bo
    {
        dim3 grid(DIM / 64, SEQ / 64);
        gemm_kernel<<<grid, 256, 0, stream>>>(h1, wo, bo, x, x2, SEQ, DIM, DIM, 0);
    }
    // 7. h2 = gamma1*LN(x2)+beta1
    ln_kernel<<<SEQ, 256, 0, stream>>>(x2, h2, gammas, betas, 1);
    // 8. f1 = gelu(h2@w1 + b1)
    {
        dim3 grid(FFD / 64, SEQ / 64);
        gemm_kernel<<<grid, 256, 0, stream>>>(h2, w1, b1, nullptr, f1, SEQ, FFD, DIM, 1);
    }
    // 9. out = x2 + f1@w2 + b2
    {
        dim3 grid(DIM / 64, SEQ / 64);
        gemm_kernel<<<grid, 256, 0, stream>>>(f1, w2, b2, x2, out, SEQ, DIM, FFD, 0);
    }
}

// Round 3
// 279.377 us; speedup vs baseline: 6.6247x; 2.1838x over previous
//
#include <hip/hip_runtime.h>
#include <math.h>

constexpr int SEQ  = 4096;
constexpr int DIM  = 512;
constexpr int NH   = 8;
constexpr int HDIM = 64;
constexpr int FFD  = 2048;

typedef unsigned short u16;
typedef __attribute__((ext_vector_type(8))) short bf16x8;
typedef __attribute__((ext_vector_type(4))) float f32x4;
typedef __attribute__((ext_vector_type(8))) unsigned short u16x8;

static __device__ __forceinline__ u16 f2bf(float x) {
    union { float f; unsigned int u; } v; v.f = x;
    unsigned int r = v.u + 0x7fff + ((v.u >> 16) & 1);
    return (u16)(r >> 16);
}
static __device__ __forceinline__ float bf2f(u16 h) {
    union { unsigned int u; float f; } v; v.u = ((unsigned int)h) << 16;
    return v.f;
}

// ---------------- weight convert + transpose: dst[n][k] = bf16(src[k][n]) ----------------
__global__ void wconv(const float* __restrict__ src, u16* __restrict__ dst, int K, int N) {
    __shared__ float tile[32][33];
    int n0 = blockIdx.x * 32, k0 = blockIdx.y * 32;
    int tx = threadIdx.x & 31, ty = threadIdx.x >> 5;   // 32 x 8
#pragma unroll
    for (int i = 0; i < 4; i++) {
        int kk = ty + i * 8;
        tile[kk][tx] = src[(size_t)(k0 + kk) * N + n0 + tx];
    }
    __syncthreads();
#pragma unroll
    for (int i = 0; i < 4; i++) {
        int nn = ty + i * 8;
        dst[(size_t)(n0 + nn) * K + k0 + tx] = f2bf(tile[tx][nn]);
    }
}

// ---------------- LayerNorm (+affine), f32 in -> bf16 out ----------------
__global__ void ln_kernel(const float* __restrict__ x, u16* __restrict__ out,
                          const float* __restrict__ gammas, const float* __restrict__ betas,
                          int gi) {
    int row = blockIdx.x;
    int t = threadIdx.x;                 // 256 threads
    const float* xr = x + (size_t)row * DIM;
    float v0 = xr[t], v1 = xr[t + 256];
    __shared__ float rs[256], rq[256];
    rs[t] = v0 + v1;
    rq[t] = v0 * v0 + v1 * v1;
    __syncthreads();
    for (int o = 128; o > 0; o >>= 1) {
        if (t < o) { rs[t] += rs[t + o]; rq[t] += rq[t + o]; }
        __syncthreads();
    }
    float mean = rs[0] / DIM;
    float var  = rq[0] / DIM - mean * mean;
    float rstd = rsqrtf(var + 1e-5f);
    float g = gammas[gi], b = betas[gi];
    out[(size_t)row * DIM + t]       = f2bf(g * ((v0 - mean) * rstd) + b);
    out[(size_t)row * DIM + t + 256] = f2bf(g * ((v1 - mean) * rstd) + b);
}

// ---------------- bf16 MFMA GEMM: C(M,N) = A(M,K) @ WT(N,K)^T ----------------
// flags: 1 = bf16 out, 2 = gelu, 4 = split into 3x512 outputs (Cq/Ck/Cv)
// tile BM=128 x BN=64, BK=64; 4 waves stacked in M, each 32x64 (2x4 frags)
constexpr int FLAG_BF16 = 1, FLAG_GELU = 2, FLAG_SPLIT = 4;

__global__ __launch_bounds__(256) void gemm_bf16(
    const u16* __restrict__ A, const u16* __restrict__ WT,
    const float* __restrict__ bias, const float* __restrict__ resid,
    void* __restrict__ Cq, void* __restrict__ Ck, void* __restrict__ Cv,
    int M, int N, int K, int flags)
{
    __shared__ __align__(16) u16 At[128 * 64];   // [row][k] swizzled, 16 KB
    __shared__ __align__(16) u16 Bt[64 * 64];    // [n][k]  swizzled,  8 KB
    const int t = threadIdx.x, lane = t & 63, w = t >> 6;
    const int n0 = blockIdx.x * 64, m0 = blockIdx.y * 128;
    const int l15 = lane & 15, l4 = lane >> 4;

    f32x4 acc[2][4];
#pragma unroll
    for (int m = 0; m < 2; m++)
#pragma unroll
        for (int n = 0; n < 4; n++) acc[m][n] = (f32x4){0.f, 0.f, 0.f, 0.f};

    for (int k0 = 0; k0 < K; k0 += 64) {
        // stage A: 128 rows x 128 B = 1024 chunks of 16 B, 4 per thread
#pragma unroll
        for (int p = 0; p < 4; p++) {
            int c = p * 256 + t;
            int r = c >> 3, j = c & 7;
            u16x8 v = *(const u16x8*)(A + (size_t)(m0 + r) * K + k0 + j * 8);
            *(u16x8*)((char*)At + r * 128 + ((j * 16) ^ ((r & 7) << 4))) = v;
        }
        // stage B: 64 rows x 128 B = 512 chunks, 2 per thread
#pragma unroll
        for (int p = 0; p < 2; p++) {
            int c = p * 256 + t;
            int r = c >> 3, j = c & 7;
            u16x8 v = *(const u16x8*)(WT + (size_t)(n0 + r) * K + k0 + j * 8);
            *(u16x8*)((char*)Bt + r * 128 + ((j * 16) ^ ((r & 7) << 4))) = v;
        }
        __syncthreads();
#pragma unroll
        for (int kk = 0; kk < 2; kk++) {
            bf16x8 af[2], bfr[4];
#pragma unroll
            for (int m = 0; m < 2; m++) {
                int row = w * 32 + m * 16 + l15;
                af[m] = *(bf16x8*)((char*)At + row * 128 +
                                   ((kk * 64 + l4 * 16) ^ ((row & 7) << 4)));
            }
#pragma unroll
            for (int n = 0; n < 4; n++) {
                int row = n * 16 + l15;
                bfr[n] = *(bf16x8*)((char*)Bt + row * 128 +
                                    ((kk * 64 + l4 * 16) ^ ((row & 7) << 4)));
            }
#pragma unroll
            for (int m = 0; m < 2; m++)
#pragma unroll
                for (int n = 0; n < 4; n++)
                    acc[m][n] = __builtin_amdgcn_mfma_f32_16x16x32_bf16(
                        af[m], bfr[n], acc[m][n], 0, 0, 0);
        }
        __syncthreads();
    }

    // epilogue
    const int which = n0 >> 9;        // split: which of q/k/v
    const int nloc0 = n0 & 511;
#pragma unroll
    for (int m = 0; m < 2; m++)
#pragma unroll
        for (int rr = 0; rr < 4; rr++) {
            int row = m0 + w * 32 + m * 16 + l4 * 4 + rr;
#pragma unroll
            for (int n = 0; n < 4; n++) {
                int colg = n0 + n * 16 + l15;
                float cv = acc[m][n][rr];
                if (bias) cv += bias[colg];
                if (flags & FLAG_GELU) cv = 0.5f * cv * (1.0f + erff(cv * 0.70710678118f));
                if (resid) cv += resid[(size_t)row * N + colg];
                if (flags & FLAG_SPLIT) {
                    u16* dst = which == 0 ? (u16*)Cq : which == 1 ? (u16*)Ck : (u16*)Cv;
                    dst[(size_t)row * 512 + nloc0 + n * 16 + l15] = f2bf(cv);
                } else if (flags & FLAG_BF16) {
                    ((u16*)Cq)[(size_t)row * N + colg] = f2bf(cv);
                } else {
                    ((float*)Cq)[(size_t)row * N + colg] = cv;
                }
            }
        }
}

// ---------------- RoPE (in-place on bf16 q and k) ----------------
__global__ void rope_kernel(u16* __restrict__ q, u16* __restrict__ k) {
    int idx = blockIdx.x * blockDim.x + threadIdx.x;   // SEQ*NH*16
    if (idx >= SEQ * NH * 16) return;
    int i = idx & 15;
    int h = (idx >> 4) & (NH - 1);
    int s = idx >> 7;
    float invf = expf(-(2.0f * i / 32.0f) * logf(10000.0f));
    float freq = (float)s * invf;
    float c = cosf(freq), sn = sinf(freq);
    size_t base = (size_t)s * DIM + h * HDIM + 2 * i;
    unsigned int uq = *(unsigned int*)(q + base);
    float x1 = bf2f((u16)(uq & 0xffff)), x2 = bf2f((u16)(uq >> 16));
    unsigned int r0 = f2bf(x1 * c - x2 * sn) | ((unsigned int)f2bf(x2 * c + x1 * sn) << 16);
    *(unsigned int*)(q + base) = r0;
    unsigned int uk = *(unsigned int*)(k + base);
    x1 = bf2f((u16)(uk & 0xffff)); x2 = bf2f((u16)(uk >> 16));
    unsigned int r1 = f2bf(x1 * c - x2 * sn) | ((unsigned int)f2bf(x2 * c + x1 * sn) << 16);
    *(unsigned int*)(k + base) = r1;
}

// ---------------- per-head transpose: src (S, NH*HD) bf16 -> dst (NH, HD, S) bf16 ----------------
__global__ void transpose_hd(const u16* __restrict__ src, u16* __restrict__ dst) {
    __shared__ __align__(16) u16 tile[64][80];     // pad to 160 B stride
    int h = blockIdx.y;
    int s0 = blockIdx.x * 64;
    int t = threadIdx.x;               // 256
#pragma unroll
    for (int p = 0; p < 2; p++) {
        int c = p * 256 + t;
        int r = c >> 3, j = c & 7;
        u16x8 v = *(const u16x8*)(src + (size_t)(s0 + r) * DIM + h * HDIM + j * 8);
        *(u16x8*)&tile[r][j * 8] = v;
    }
    __syncthreads();
#pragma unroll
    for (int p = 0; p < 2; p++) {
        int c = p * 256 + t;
        int d = c >> 3, j = c & 7;
        u16x8 v;
#pragma unroll
        for (int i = 0; i < 8; i++) v[i] = tile[j * 8 + i][d];
        *(u16x8*)(dst + ((size_t)h * HDIM + d) * SEQ + s0 + j * 8) = v;
    }
}

// ---------------- flash attention, bf16 MFMA, bf16 in/out ----------------
__global__ __launch_bounds__(256) void fattn_kernel(
    const u16* __restrict__ q, const u16* __restrict__ k,
    const u16* __restrict__ vT, const int* __restrict__ mask,
    u16* __restrict__ out)
{
    __shared__ __align__(16) u16 k_s[64 * 64];        // [key][d], swizzled
    __shared__ __align__(16) u16 vt_s[64 * 64];       // [d][key], swizzled
    __shared__ __align__(16) u16 p_s[4][16 * 64];     // per-wave [q][key], swizzled

    const int t = threadIdx.x;
    const int lane = t & 63;
    const int w = t >> 6;
    const int h = blockIdx.x;
    const int q0 = blockIdx.y * 64;

    // Q fragments straight from global: row q0+w*16+(l&15), d = (l>>4)*8 (+32)
    const u16* qrow = q + (size_t)(q0 + w * 16 + (lane & 15)) * DIM + h * HDIM;
    bf16x8 qf0 = *(const bf16x8*)(qrow + (lane >> 4) * 8);
    bf16x8 qf1 = *(const bf16x8*)(qrow + (lane >> 4) * 8 + 32);

    f32x4 O[4];
    float mrun[4], lrun[4];
#pragma unroll
    for (int dt = 0; dt < 4; dt++) O[dt] = (f32x4){0.f, 0.f, 0.f, 0.f};
#pragma unroll
    for (int r = 0; r < 4; r++) { mrun[r] = -INFINITY; lrun[r] = 0.f; }

    char* pbase = (char*)p_s[w];
    const int prow = lane & 15;
    const int psw  = (prow & 7) << 4;

    for (int kb = 0; kb < SEQ; kb += 64) {
        // ---- stage K tile [key][d] and V^T tile [d][key] (both swizzled) ----
#pragma unroll
        for (int p = 0; p < 2; p++) {
            int c = p * 256 + t;
            int r = c >> 3, j = c & 7;
            u16x8 kv = *(const u16x8*)(k + (size_t)(kb + r) * DIM + h * HDIM + j * 8);
            *(u16x8*)((char*)k_s + r * 128 + ((j * 16) ^ ((r & 7) << 4))) = kv;
            u16x8 vv = *(const u16x8*)(vT + ((size_t)h * HDIM + r) * SEQ + kb + j * 8);
            *(u16x8*)((char*)vt_s + r * 128 + ((j * 16) ^ ((r & 7) << 4))) = vv;
        }
        __syncthreads();

        // ---- QK^T ----
        f32x4 sacc[4];
#pragma unroll
        for (int kt = 0; kt < 4; kt++) {
            sacc[kt] = (f32x4){0.f, 0.f, 0.f, 0.f};
            int key = kt * 16 + (lane & 15);
            int ksw = (key & 7) << 4;
            char* kbase = (char*)k_s + key * 128;
            bf16x8 b0 = *(bf16x8*)(kbase + (((lane >> 4) * 16)      ^ ksw));
            bf16x8 b1 = *(bf16x8*)(kbase + (((lane >> 4) * 16 + 64) ^ ksw));
            sacc[kt] = __builtin_amdgcn_mfma_f32_16x16x32_bf16(qf0, b0, sacc[kt], 0, 0, 0);
            sacc[kt] = __builtin_amdgcn_mfma_f32_16x16x32_bf16(qf1, b1, sacc[kt], 0, 0, 0);
        }

        // ---- mask + scale ----
#pragma unroll
        for (int kt = 0; kt < 4; kt++) {
            int mk = mask[kb + kt * 16 + (lane & 15)];
            float sc = mk ? 0.125f : 0.0f;
            float ad = mk ? 0.0f : -1e9f;
#pragma unroll
            for (int r = 0; r < 4; r++) sacc[kt][r] = sacc[kt][r] * sc + ad;
        }

        // ---- online softmax ----
        float mnew[4], alpha[4];
#pragma unroll
        for (int r = 0; r < 4; r++) {
            float tm = fmaxf(fmaxf(sacc[0][r], sacc[1][r]), fmaxf(sacc[2][r], sacc[3][r]));
#pragma unroll
            for (int off = 1; off < 16; off <<= 1)
                tm = fmaxf(tm, __shfl_xor(tm, off, 64));
            mnew[r] = fmaxf(mrun[r], tm);
            alpha[r] = __expf(mrun[r] - mnew[r]);
            mrun[r] = mnew[r];
        }
        float rsum[4] = {0.f, 0.f, 0.f, 0.f};
#pragma unroll
        for (int kt = 0; kt < 4; kt++)
#pragma unroll
            for (int r = 0; r < 4; r++) {
                float p = __expf(sacc[kt][r] - mnew[r]);
                sacc[kt][r] = p;
                rsum[r] += p;
            }
#pragma unroll
        for (int r = 0; r < 4; r++) {
            float s = rsum[r];
#pragma unroll
            for (int off = 1; off < 16; off <<= 1)
                s += __shfl_xor(s, off, 64);
            lrun[r] = lrun[r] * alpha[r] + s;
        }
#pragma unroll
        for (int dt = 0; dt < 4; dt++)
#pragma unroll
            for (int r = 0; r < 4; r++) O[dt][r] *= alpha[r];

        // ---- P -> per-wave LDS (bf16, swizzled) ----
#pragma unroll
        for (int kt = 0; kt < 4; kt++)
#pragma unroll
            for (int r = 0; r < 4; r++) {
                int row = (lane >> 4) * 4 + r;
                int col = kt * 16 + (lane & 15);
                *(u16*)(pbase + ((row * 128) + ((col * 2) ^ ((row & 7) << 4))))
                    = f2bf(sacc[kt][r]);
            }

        // ---- PV ----
#pragma unroll
        for (int half = 0; half < 2; half++) {
            bf16x8 pa = *(bf16x8*)(pbase + prow * 128 +
                                   (((lane >> 4) * 16 + half * 64) ^ psw));
#pragma unroll
            for (int dt = 0; dt < 4; dt++) {
                int d = dt * 16 + (lane & 15);
                bf16x8 vb = *(bf16x8*)((char*)vt_s + d * 128 +
                                       (((lane >> 4) * 16 + half * 64) ^ ((d & 7) << 4)));
                O[dt] = __builtin_amdgcn_mfma_f32_16x16x32_bf16(pa, vb, O[dt], 0, 0, 0);
            }
        }
        __syncthreads();
    }

    // ---- epilogue (bf16 out) ----
#pragma unroll
    for (int dt = 0; dt < 4; dt++)
#pragma unroll
        for (int r = 0; r < 4; r++) {
            int row = q0 + w * 16 + (lane >> 4) * 4 + r;
            int col = h * HDIM + dt * 16 + (lane & 15);
            out[(size_t)row * DIM + col] = f2bf(O[dt][r] / lrun[r]);
        }
}

extern "C" void kernel_launch(void* const* d_in, const int* in_sizes, int n_in,
                              void* d_out, int out_size, void* d_ws, size_t ws_size,
                              hipStream_t stream) {
    const float* x      = (const float*)d_in[0];
    const float* gammas = (const float*)d_in[1];
    const float* betas  = (const float*)d_in[2];
    const float* wq     = (const float*)d_in[3];
    const float* wk     = (const float*)d_in[4];
    const float* wv     = (const float*)d_in[5];
    const float* wo     = (const float*)d_in[6];
    const float* bo     = (const float*)d_in[7];
    const float* w1     = (const float*)d_in[8];
    const float* b1     = (const float*)d_in[9];
    const float* w2     = (const float*)d_in[10];
    const float* b2     = (const float*)d_in[11];
    const int*   mask   = (const int*)d_in[12];
    float* out = (float*)d_out;

    // ---- workspace layout (bytes) ----
    char* wsb = (char*)d_ws;
    u16*   h1b   = (u16*)(wsb + 0);                       // 4 MB; reused as attn-out; part of f1b
    u16*   kb    = (u16*)(wsb + (4ull  << 20));           // 4 MB; part of f1b
    u16*   vb    = (u16*)(wsb + (8ull  << 20));           // 4 MB; part of f1b
    u16*   vTb   = (u16*)(wsb + (12ull << 20));           // 4 MB; part of f1b
    u16*   qb    = (u16*)(wsb + (16ull << 20));           // 4 MB; reused as h2b
    float* x2    = (float*)(wsb + (20ull << 20));         // 8 MB
    u16*   wqkvT = (u16*)(wsb + (28ull << 20));           // 1.5 MB (1536 x 512)
    u16*   woT   = wqkvT + 1536 * 512;                    // 0.5 MB
    u16*   w1T   = woT   + 512 * 512;                     // 2 MB (2048 x 512)
    u16*   w2T   = w1T   + 2048 * 512;                    // 2 MB (512 x 2048)
    u16*   f1b   = h1b;                                   // 16 MB spanning slots 0-3
    u16*   h2b   = qb;
    u16*   attnb = h1b;

    // 0. weight convert + transpose (bf16, N x K)
    wconv<<<dim3(DIM / 32, DIM / 32), 256, 0, stream>>>(wq, wqkvT, DIM, DIM);
    wconv<<<dim3(DIM / 32, DIM / 32), 256, 0, stream>>>(wk, wqkvT + 512 * 512, DIM, DIM);
    wconv<<<dim3(DIM / 32, DIM / 32), 256, 0, stream>>>(wv, wqkvT + 1024 * 512, DIM, DIM);
    wconv<<<dim3(DIM / 32, DIM / 32), 256, 0, stream>>>(wo, woT, DIM, DIM);
    wconv<<<dim3(FFD / 32, DIM / 32), 256, 0, stream>>>(w1, w1T, DIM, FFD);
    wconv<<<dim3(DIM / 32, FFD / 32), 256, 0, stream>>>(w2, w2T, FFD, DIM);

    // 1. h1 = LN(x) (bf16)
    ln_kernel<<<SEQ, 256, 0, stream>>>(x, h1b, gammas, betas, 0);
    // 2. fused QKV projection (split outputs)
    gemm_bf16<<<dim3(1536 / 64, SEQ / 128), 256, 0, stream>>>(
        h1b, wqkvT, nullptr, nullptr, qb, kb, vb, SEQ, 1536, DIM, FLAG_SPLIT | FLAG_BF16);
    // 3. RoPE in-place on q,k
    rope_kernel<<<(SEQ * NH * 16) / 256, 256, 0, stream>>>(qb, kb);
    // 4. vT = per-head transpose of v
    transpose_hd<<<dim3(SEQ / 64, NH), 256, 0, stream>>>(vb, vTb);
    // 5. attention (bf16 out into attnb)
    fattn_kernel<<<dim3(NH, SEQ / 64), 256, 0, stream>>>(qb, kb, vTb, mask, attnb);
    // 6. x2 = x + attn@wo + bo (f32)
    gemm_bf16<<<dim3(DIM / 64, SEQ / 128), 256, 0, stream>>>(
        attnb, woT, bo, x, x2, nullptr, nullptr, SEQ, DIM, DIM, 0);
    // 7. h2 = LN(x2) (bf16)
    ln_kernel<<<SEQ, 256, 0, stream>>>(x2, h2b, gammas, betas, 1);
    // 8. f1 = gelu(h2@w1 + b1) (bf16)
    gemm_bf16<<<dim3(FFD / 64, SEQ / 128), 256, 0, stream>>>(
        h2b, w1T, b1, nullptr, f1b, nullptr, nullptr, SEQ, FFD, DIM, FLAG_BF16 | FLAG_GELU);
    // 9. out = x2 + f1@w2 + b2 (f32)
    gemm_bf16<<<dim3(DIM / 64, SEQ / 128), 256, 0, stream>>>(
        f1b, w2T, b2, x2, out, nullptr, nullptr, SEQ, DIM, FFD, 0);
}

// Round 4
// 245.868 us; speedup vs baseline: 7.5275x; 1.1363x over previous
//
#include <hip/hip_runtime.h>
#include <math.h>

constexpr int SEQ  = 4096;
constexpr int DIM  = 512;
constexpr int NH   = 8;
constexpr int HDIM = 64;
constexpr int FFD  = 2048;

typedef unsigned short u16;
typedef __attribute__((ext_vector_type(8))) short bf16x8;
typedef __attribute__((ext_vector_type(4))) float f32x4;
typedef __attribute__((ext_vector_type(8))) unsigned short u16x8;

static __device__ __forceinline__ u16 f2bf(float x) {
    union { float f; unsigned int u; } v; v.f = x;
    unsigned int r = v.u + 0x7fff + ((v.u >> 16) & 1);
    return (u16)(r >> 16);
}
static __device__ __forceinline__ float bf2f(u16 h) {
    union { unsigned int u; float f; } v; v.u = ((unsigned int)h) << 16;
    return v.f;
}
static __device__ __forceinline__ unsigned int cvtpk(float lo, float hi) {
    unsigned int r;
    asm volatile("v_cvt_pk_bf16_f32 %0, %1, %2" : "=v"(r) : "v"(lo), "v"(hi));
    return r;
}
static __device__ __forceinline__ void gload_lds16(const void* g, void* l) {
    __builtin_amdgcn_global_load_lds(
        (const __attribute__((address_space(1))) unsigned int*)g,
        (__attribute__((address_space(3))) unsigned int*)l, 16, 0, 0);
}

// ---------------- additive mask precompute ----------------
__global__ void maskf_kernel(const int* __restrict__ mask, float* __restrict__ mf) {
    int i = blockIdx.x * 256 + threadIdx.x;
    if (i < SEQ) mf[i] = mask[i] ? 0.0f : -1e9f;
}

// ---------------- weight convert + transpose: dst[n][k] = bf16(scale*src[k][n]) ----------------
__global__ void wconv(const float* __restrict__ src, u16* __restrict__ dst, int K, int N,
                      float scale) {
    __shared__ float tile[32][33];
    int n0 = blockIdx.x * 32, k0 = blockIdx.y * 32;
    int tx = threadIdx.x & 31, ty = threadIdx.x >> 5;   // 32 x 8
#pragma unroll
    for (int i = 0; i < 4; i++) {
        int kk = ty + i * 8;
        tile[kk][tx] = src[(size_t)(k0 + kk) * N + n0 + tx];
    }
    __syncthreads();
#pragma unroll
    for (int i = 0; i < 4; i++) {
        int nn = ty + i * 8;
        dst[(size_t)(n0 + nn) * K + k0 + tx] = f2bf(scale * tile[tx][nn]);
    }
}

// ---------------- LayerNorm (+affine), f32 in -> bf16 out ----------------
__global__ void ln_kernel(const float* __restrict__ x, u16* __restrict__ out,
                          const float* __restrict__ gammas, const float* __restrict__ betas,
                          int gi) {
    int row = blockIdx.x;
    int t = threadIdx.x;                 // 256 threads
    const float* xr = x + (size_t)row * DIM;
    float v0 = xr[t], v1 = xr[t + 256];
    __shared__ float rs[256], rq[256];
    rs[t] = v0 + v1;
    rq[t] = v0 * v0 + v1 * v1;
    __syncthreads();
    for (int o = 128; o > 0; o >>= 1) {
        if (t < o) { rs[t] += rs[t + o]; rq[t] += rq[t + o]; }
        __syncthreads();
    }
    float mean = rs[0] / DIM;
    float var  = rq[0] / DIM - mean * mean;
    float rstd = rsqrtf(var + 1e-5f);
    float g = gammas[gi], b = betas[gi];
    out[(size_t)row * DIM + t]       = f2bf(g * ((v0 - mean) * rstd) + b);
    out[(size_t)row * DIM + t + 256] = f2bf(g * ((v1 - mean) * rstd) + b);
}

// ---------------- bf16 MFMA GEMM: C(M,N) = A(M,K) @ WT(N,K)^T ----------------
constexpr int FLAG_BF16 = 1, FLAG_GELU = 2, FLAG_SPLIT = 4;

__global__ __launch_bounds__(256) void gemm_bf16(
    const u16* __restrict__ A, const u16* __restrict__ WT,
    const float* __restrict__ bias, const float* __restrict__ resid,
    void* __restrict__ Cq, void* __restrict__ Ck, void* __restrict__ Cv,
    int M, int N, int K, int flags)
{
    __shared__ __align__(16) u16 At[128 * 64];   // [row][k] swizzled, 16 KB
    __shared__ __align__(16) u16 Bt[64 * 64];    // [n][k]  swizzled,  8 KB
    const int t = threadIdx.x, lane = t & 63, w = t >> 6;
    const int n0 = blockIdx.x * 64, m0 = blockIdx.y * 128;
    const int l15 = lane & 15, l4 = lane >> 4;

    f32x4 acc[2][4];
#pragma unroll
    for (int m = 0; m < 2; m++)
#pragma unroll
        for (int n = 0; n < 4; n++) acc[m][n] = (f32x4){0.f, 0.f, 0.f, 0.f};

    for (int k0 = 0; k0 < K; k0 += 64) {
        // async stage A: 1024 16B chunks; source pre-swizzled so linear LDS = swizzled image
#pragma unroll
        for (int i = 0; i < 4; i++) {
            int c = (w * 4 + i) * 64 + lane;
            int r = c >> 3, j = (c & 7) ^ (r & 7);
            gload_lds16(A + (size_t)(m0 + r) * K + k0 + j * 8, (char*)At + (w * 4 + i) * 1024);
        }
#pragma unroll
        for (int i = 0; i < 2; i++) {
            int c = (w * 2 + i) * 64 + lane;
            int r = c >> 3, j = (c & 7) ^ (r & 7);
            gload_lds16(WT + (size_t)(n0 + r) * K + k0 + j * 8, (char*)Bt + (w * 2 + i) * 1024);
        }
        asm volatile("s_waitcnt vmcnt(0)" ::: "memory");
        __syncthreads();
        __builtin_amdgcn_s_setprio(1);
#pragma unroll
        for (int kk = 0; kk < 2; kk++) {
            bf16x8 af[2], bfr[4];
#pragma unroll
            for (int m = 0; m < 2; m++) {
                int row = w * 32 + m * 16 + l15;
                af[m] = *(bf16x8*)((char*)At + row * 128 +
                                   ((kk * 64 + l4 * 16) ^ ((row & 7) << 4)));
            }
#pragma unroll
            for (int n = 0; n < 4; n++) {
                int row = n * 16 + l15;
                bfr[n] = *(bf16x8*)((char*)Bt + row * 128 +
                                    ((kk * 64 + l4 * 16) ^ ((row & 7) << 4)));
            }
#pragma unroll
            for (int m = 0; m < 2; m++)
#pragma unroll
                for (int n = 0; n < 4; n++)
                    acc[m][n] = __builtin_amdgcn_mfma_f32_16x16x32_bf16(
                        af[m], bfr[n], acc[m][n], 0, 0, 0);
        }
        __builtin_amdgcn_s_setprio(0);
        __syncthreads();
    }

    // epilogue
    const int which = n0 >> 9;        // split: which of q/k/v
    const int nloc0 = n0 & 511;
#pragma unroll
    for (int m = 0; m < 2; m++)
#pragma unroll
        for (int rr = 0; rr < 4; rr++) {
            int row = m0 + w * 32 + m * 16 + l4 * 4 + rr;
#pragma unroll
            for (int n = 0; n < 4; n++) {
                int colg = n0 + n * 16 + l15;
                float cv = acc[m][n][rr];
                if (bias) cv += bias[colg];
                if (flags & FLAG_GELU) cv = 0.5f * cv * (1.0f + erff(cv * 0.70710678118f));
                if (resid) cv += resid[(size_t)row * N + colg];
                if (flags & FLAG_SPLIT) {
                    u16* dst = which == 0 ? (u16*)Cq : which == 1 ? (u16*)Ck : (u16*)Cv;
                    dst[(size_t)row * 512 + nloc0 + n * 16 + l15] = f2bf(cv);
                } else if (flags & FLAG_BF16) {
                    ((u16*)Cq)[(size_t)row * N + colg] = f2bf(cv);
                } else {
                    ((float*)Cq)[(size_t)row * N + colg] = cv;
                }
            }
        }
}

// ---------------- RoPE (in-place on bf16 q and k) ----------------
__global__ void rope_kernel(u16* __restrict__ q, u16* __restrict__ k) {
    int idx = blockIdx.x * blockDim.x + threadIdx.x;   // SEQ*NH*16
    if (idx >= SEQ * NH * 16) return;
    int i = idx & 15;
    int h = (idx >> 4) & (NH - 1);
    int s = idx >> 7;
    float invf = expf(-(2.0f * i / 32.0f) * logf(10000.0f));
    float freq = (float)s * invf;
    float c = cosf(freq), sn = sinf(freq);
    size_t base = (size_t)s * DIM + h * HDIM + 2 * i;
    unsigned int uq = *(unsigned int*)(q + base);
    float x1 = bf2f((u16)(uq & 0xffff)), x2 = bf2f((u16)(uq >> 16));
    *(unsigned int*)(q + base) = cvtpk(x1 * c - x2 * sn, x2 * c + x1 * sn);
    unsigned int uk = *(unsigned int*)(k + base);
    x1 = bf2f((u16)(uk & 0xffff)); x2 = bf2f((u16)(uk >> 16));
    *(unsigned int*)(k + base) = cvtpk(x1 * c - x2 * sn, x2 * c + x1 * sn);
}

// ---------------- per-head transpose: src (S, NH*HD) bf16 -> dst (NH, HD, S) bf16 ----------------
__global__ void transpose_hd(const u16* __restrict__ src, u16* __restrict__ dst) {
    __shared__ __align__(16) u16 tile[64][80];
    int h = blockIdx.y;
    int s0 = blockIdx.x * 64;
    int t = threadIdx.x;               // 256
#pragma unroll
    for (int p = 0; p < 2; p++) {
        int c = p * 256 + t;
        int r = c >> 3, j = c & 7;
        u16x8 v = *(const u16x8*)(src + (size_t)(s0 + r) * DIM + h * HDIM + j * 8);
        *(u16x8*)&tile[r][j * 8] = v;
    }
    __syncthreads();
#pragma unroll
    for (int p = 0; p < 2; p++) {
        int c = p * 256 + t;
        int d = c >> 3, j = c & 7;
        u16x8 v;
#pragma unroll
        for (int i = 0; i < 8; i++) v[i] = tile[j * 8 + i][d];
        *(u16x8*)(dst + ((size_t)h * HDIM + d) * SEQ + s0 + j * 8) = v;
    }
}

// ---------------- flash attention, swapped-QK^T, bf16 MFMA ----------------
// grid (NH, SEQ/64), 256 threads = 4 waves, 16 q-rows/wave.
// QK^T computed as S^T = mfma(A=K, B=Q): lane holds 16 scores of ONE q-row (l&15).
// PV computed as O^T = mfma(A=V^T, B=P): O regs: d = dt*16+4g+r, q = l&15.
__global__ __launch_bounds__(256) void fattn_kernel(
    const u16* __restrict__ q, const u16* __restrict__ k,
    const u16* __restrict__ vT, const float* __restrict__ maskf,
    u16* __restrict__ out)
{
    __shared__ __align__(16) u16 k_s[2][64 * 64];     // [buf][key][d] swizzled image
    __shared__ __align__(16) u16 vt_s[2][64 * 64];    // [buf][d][key] swizzled image
    __shared__ __align__(16) u16 p_s[4][16 * 64];     // per-wave [q][key] swizzled

    const int t = threadIdx.x;
    const int lane = t & 63;
    const int w = t >> 6;
    const int h = blockIdx.x;
    const int q0 = blockIdx.y * 64;
    const int l15 = lane & 15, g = lane >> 4;

    // Q as B-frag, straight from global: q-row = q0+w*16+l15, d = g*8+j (+32)
    const u16* qrow = q + (size_t)(q0 + w * 16 + l15) * DIM + h * HDIM;
    bf16x8 qf0 = *(const bf16x8*)(qrow + g * 8);
    bf16x8 qf1 = *(const bf16x8*)(qrow + g * 8 + 32);

    f32x4 O[4];                       // O^T: [dt], reg r -> d = dt*16+4g+r, col q = l15
#pragma unroll
    for (int dt = 0; dt < 4; dt++) O[dt] = (f32x4){0.f, 0.f, 0.f, 0.f};
    float mrun = -INFINITY, lrun = 0.f;

    char* pbase = (char*)p_s[w];
    const int psw = (l15 & 7) << 4;

    // async stage of one 64-key tile (K + V^T) into buf; source pre-swizzled
    auto stage = [&](int buf, int kb2) {
#pragma unroll
        for (int i = 0; i < 2; i++) {
            int c = (w * 2 + i) * 64 + lane;
            int r = c >> 3, j = (c & 7) ^ (r & 7);
            gload_lds16(k + (size_t)(kb2 + r) * DIM + h * HDIM + j * 8,
                        (char*)k_s + buf * 8192 + (w * 2 + i) * 1024);
            gload_lds16(vT + ((size_t)h * HDIM + r) * SEQ + kb2 + j * 8,
                        (char*)vt_s + buf * 8192 + (w * 2 + i) * 1024);
        }
    };

    stage(0, 0);
    for (int ti = 0; ti < SEQ / 64; ti++) {
        const int cur = ti & 1;
        const int kb = ti * 64;
        asm volatile("s_waitcnt vmcnt(0)" ::: "memory");
        __syncthreads();                       // buf[cur] ready on all waves
        if (ti + 1 < SEQ / 64) stage(cur ^ 1, kb + 64);

        char* kcur = (char*)k_s + cur * 8192;
        char* vcur = (char*)vt_s + cur * 8192;

        // ---- QK^T (swapped): sacc[kt] = S^T tile, rows=keys kt*16+4g+r, col q=l15 ----
        f32x4 sacc[4];
        __builtin_amdgcn_s_setprio(1);
#pragma unroll
        for (int kt = 0; kt < 4; kt++) {
            sacc[kt] = (f32x4){0.f, 0.f, 0.f, 0.f};
            int key = kt * 16 + l15;
            int ksw = (key & 7) << 4;
            char* kbase = kcur + key * 128;
            bf16x8 a0 = *(bf16x8*)(kbase + ((g * 16)      ^ ksw));
            bf16x8 a1 = *(bf16x8*)(kbase + ((g * 16 + 64) ^ ksw));
            sacc[kt] = __builtin_amdgcn_mfma_f32_16x16x32_bf16(a0, qf0, sacc[kt], 0, 0, 0);
            sacc[kt] = __builtin_amdgcn_mfma_f32_16x16x32_bf16(a1, qf1, sacc[kt], 0, 0, 0);
        }
        __builtin_amdgcn_s_setprio(0);

        // ---- additive mask + local max ----
        float tmax = -INFINITY;
#pragma unroll
        for (int kt = 0; kt < 4; kt++) {
            float4 mf = *(const float4*)(maskf + kb + kt * 16 + g * 4);
            sacc[kt][0] += mf.x; sacc[kt][1] += mf.y;
            sacc[kt][2] += mf.z; sacc[kt][3] += mf.w;
#pragma unroll
            for (int r = 0; r < 4; r++) tmax = fmaxf(tmax, sacc[kt][r]);
        }
        tmax = fmaxf(tmax, __shfl_xor(tmax, 16, 64));
        tmax = fmaxf(tmax, __shfl_xor(tmax, 32, 64));

        float mnew = fmaxf(mrun, tmax);
        float alpha = __expf(mrun - mnew);
        mrun = mnew;

        float rsum = 0.f;
#pragma unroll
        for (int kt = 0; kt < 4; kt++)
#pragma unroll
            for (int r = 0; r < 4; r++) {
                float p = __expf(sacc[kt][r] - mnew);
                sacc[kt][r] = p;
                rsum += p;
            }
        rsum += __shfl_xor(rsum, 16, 64);
        rsum += __shfl_xor(rsum, 32, 64);
        lrun = lrun * alpha + rsum;
#pragma unroll
        for (int dt = 0; dt < 4; dt++)
#pragma unroll
            for (int r = 0; r < 4; r++) O[dt][r] *= alpha;

        // ---- P pack (cvt_pk) -> per-wave LDS [q][key] ----
#pragma unroll
        for (int kt = 0; kt < 4; kt++)
#pragma unroll
            for (int pi = 0; pi < 2; pi++) {
                unsigned int pk = cvtpk(sacc[kt][2 * pi], sacc[kt][2 * pi + 1]);
                int col = (kt * 16 + g * 4 + 2 * pi) * 2;      // byte col
                *(unsigned int*)(pbase + l15 * 128 + (col ^ psw)) = pk;
            }

        // ---- PV: O^T += V^T(A) @ P(B) ----
        __builtin_amdgcn_s_setprio(1);
#pragma unroll
        for (int h2 = 0; h2 < 2; h2++) {
            bf16x8 pb = *(bf16x8*)(pbase + l15 * 128 + (((h2 * 4 + g) * 16) ^ psw));
#pragma unroll
            for (int dt = 0; dt < 4; dt++) {
                int d = dt * 16 + l15;
                bf16x8 va = *(bf16x8*)(vcur + d * 128 + (((h2 * 4 + g) * 16) ^ ((d & 7) << 4)));
                O[dt] = __builtin_amdgcn_mfma_f32_16x16x32_bf16(va, pb, O[dt], 0, 0, 0);
            }
        }
        __builtin_amdgcn_s_setprio(0);
    }

    // ---- epilogue: O^T -> out rows; pack bf16 pairs along d ----
    float inv = 1.0f / lrun;
    u16* orow = out + (size_t)(q0 + w * 16 + l15) * DIM + h * HDIM;
#pragma unroll
    for (int dt = 0; dt < 4; dt++)
#pragma unroll
        for (int r = 0; r < 4; r += 2) {
            unsigned int pk = cvtpk(O[dt][r] * inv, O[dt][r + 1] * inv);
            *(unsigned int*)(orow + dt * 16 + 4 * g + r) = pk;
        }
}

extern "C" void kernel_launch(void* const* d_in, const int* in_sizes, int n_in,
                              void* d_out, int out_size, void* d_ws, size_t ws_size,
                              hipStream_t stream) {
    const float* x      = (const float*)d_in[0];
    const float* gammas = (const float*)d_in[1];
    const float* betas  = (const float*)d_in[2];
    const float* wq     = (const float*)d_in[3];
    const float* wk     = (const float*)d_in[4];
    const float* wv     = (const float*)d_in[5];
    const float* wo     = (const float*)d_in[6];
    const float* bo     = (const float*)d_in[7];
    const float* w1     = (const float*)d_in[8];
    const float* b1     = (const float*)d_in[9];
    const float* w2     = (const float*)d_in[10];
    const float* b2     = (const float*)d_in[11];
    const int*   mask   = (const int*)d_in[12];
    float* out = (float*)d_out;

    // ---- workspace layout (bytes) ----
    char* wsb = (char*)d_ws;
    u16*   h1b   = (u16*)(wsb + 0);                       // 4 MB; attn-out; part of f1b
    u16*   kb    = (u16*)(wsb + (4ull  << 20));           // 4 MB; part of f1b
    u16*   vb    = (u16*)(wsb + (8ull  << 20));           // 4 MB; part of f1b
    u16*   vTb   = (u16*)(wsb + (12ull << 20));           // 4 MB; part of f1b
    u16*   qb    = (u16*)(wsb + (16ull << 20));           // 4 MB; reused as h2b
    float* x2    = (float*)(wsb + (20ull << 20));         // 8 MB
    u16*   wqkvT = (u16*)(wsb + (28ull << 20));           // 1.5 MB
    u16*   woT   = wqkvT + 1536 * 512;                    // 0.5 MB
    u16*   w1T   = woT   + 512 * 512;                     // 2 MB
    u16*   w2T   = w1T   + 2048 * 512;                    // 2 MB
    float* maskf = (float*)(wsb + (34ull << 20));         // 16 KB
    u16*   f1b   = h1b;
    u16*   h2b   = qb;
    u16*   attnb = h1b;

    // 0. mask + weight prep (scale 1/8 folded into wq)
    maskf_kernel<<<SEQ / 256, 256, 0, stream>>>(mask, maskf);
    wconv<<<dim3(DIM / 32, DIM / 32), 256, 0, stream>>>(wq, wqkvT, DIM, DIM, 0.125f);
    wconv<<<dim3(DIM / 32, DIM / 32), 256, 0, stream>>>(wk, wqkvT + 512 * 512, DIM, DIM, 1.f);
    wconv<<<dim3(DIM / 32, DIM / 32), 256, 0, stream>>>(wv, wqkvT + 1024 * 512, DIM, DIM, 1.f);
    wconv<<<dim3(DIM / 32, DIM / 32), 256, 0, stream>>>(wo, woT, DIM, DIM, 1.f);
    wconv<<<dim3(FFD / 32, DIM / 32), 256, 0, stream>>>(w1, w1T, DIM, FFD, 1.f);
    wconv<<<dim3(DIM / 32, FFD / 32), 256, 0, stream>>>(w2, w2T, FFD, DIM, 1.f);

    // 1. h1 = LN(x) (bf16)
    ln_kernel<<<SEQ, 256, 0, stream>>>(x, h1b, gammas, betas, 0);
    // 2. fused QKV projection (q pre-scaled by 1/8)
    gemm_bf16<<<dim3(1536 / 64, SEQ / 128), 256, 0, stream>>>(
        h1b, wqkvT, nullptr, nullptr, qb, kb, vb, SEQ, 1536, DIM, FLAG_SPLIT | FLAG_BF16);
    // 3. RoPE in-place on q,k (rotation commutes with the 1/8 scale)
    rope_kernel<<<(SEQ * NH * 16) / 256, 256, 0, stream>>>(qb, kb);
    // 4. vT = per-head transpose of v
    transpose_hd<<<dim3(SEQ / 64, NH), 256, 0, stream>>>(vb, vTb);
    // 5. attention
    fattn_kernel<<<dim3(NH, SEQ / 64), 256, 0, stream>>>(qb, kb, vTb, maskf, attnb);
    // 6. x2 = x + attn@wo + bo (f32)
    gemm_bf16<<<dim3(DIM / 64, SEQ / 128), 256, 0, stream>>>(
        attnb, woT, bo, x, x2, nullptr, nullptr, SEQ, DIM, DIM, 0);
    // 7. h2 = LN(x2) (bf16)
    ln_kernel<<<SEQ, 256, 0, stream>>>(x2, h2b, gammas, betas, 1);
    // 8. f1 = gelu(h2@w1 + b1) (bf16)
    gemm_bf16<<<dim3(FFD / 64, SEQ / 128), 256, 0, stream>>>(
        h2b, w1T, b1, nullptr, f1b, nullptr, nullptr, SEQ, FFD, DIM, FLAG_BF16 | FLAG_GELU);
    // 9. out = x2 + f1@w2 + b2 (f32)
    gemm_bf16<<<dim3(DIM / 64, SEQ / 128), 256, 0, stream>>>(
        f1b, w2T, b2, x2, out, nullptr, nullptr, SEQ, DIM, FFD, 0);
}

// Round 5
// 238.466 us; speedup vs baseline: 7.7612x; 1.0310x over previous
//
#include <hip/hip_runtime.h>
#include <math.h>

constexpr int SEQ  = 4096;
constexpr int DIM  = 512;
constexpr int NH   = 8;
constexpr int HDIM = 64;
constexpr int FFD  = 2048;

typedef unsigned short u16;
typedef __attribute__((ext_vector_type(8))) short bf16x8;
typedef __attribute__((ext_vector_type(4))) float f32x4;
typedef __attribute__((ext_vector_type(8))) unsigned short u16x8;

// score scale: (1/8) * log2(e), folded into wq. Softmax computed in exp2 domain
// with static shift 8 (scores are O(0.2); softmax is shift/base invariant).
#define LOG2E      1.4426950408889634f
#define QSCALE     (0.125f * LOG2E)
#define MASK_ON    (-8.0f * LOG2E)        // unmasked: 2^(s*log2e - 8*log2e) = e^(s-8)
#define MASK_OFF   (-1.4427e9f)           // masked: exp2 underflows to exact 0

static __device__ __forceinline__ u16 f2bf(float x) {
    union { float f; unsigned int u; } v; v.f = x;
    unsigned int r = v.u + 0x7fff + ((v.u >> 16) & 1);
    return (u16)(r >> 16);
}
static __device__ __forceinline__ float bf2f(u16 h) {
    union { unsigned int u; float f; } v; v.u = ((unsigned int)h) << 16;
    return v.f;
}
static __device__ __forceinline__ unsigned int cvtpk(float lo, float hi) {
    unsigned int r;
    asm volatile("v_cvt_pk_bf16_f32 %0, %1, %2" : "=v"(r) : "v"(lo), "v"(hi));
    return r;
}
#if __has_builtin(__builtin_amdgcn_exp2f)
#define EXP2F(x) __builtin_amdgcn_exp2f(x)
#else
static __device__ __forceinline__ float exp2_asm(float x) {
    float r; asm volatile("v_exp_f32 %0, %1" : "=v"(r) : "v"(x)); return r;
}
#define EXP2F(x) exp2_asm(x)
#endif
static __device__ __forceinline__ void gload_lds16(const void* g, void* l) {
    __builtin_amdgcn_global_load_lds(
        (const __attribute__((address_space(1))) unsigned int*)g,
        (__attribute__((address_space(3))) unsigned int*)l, 16, 0, 0);
}

// ---------------- additive mask precompute (exp2 domain) ----------------
__global__ void maskf_kernel(const int* __restrict__ mask, float* __restrict__ mf) {
    int i = blockIdx.x * 256 + threadIdx.x;
    if (i < SEQ) mf[i] = mask[i] ? MASK_ON : MASK_OFF;
}

// ---------------- weight convert + transpose: dst[n][k] = bf16(scale*src[k][n]) ----------------
__global__ void wconv(const float* __restrict__ src, u16* __restrict__ dst, int K, int N,
                      float scale) {
    __shared__ float tile[32][33];
    int n0 = blockIdx.x * 32, k0 = blockIdx.y * 32;
    int tx = threadIdx.x & 31, ty = threadIdx.x >> 5;   // 32 x 8
#pragma unroll
    for (int i = 0; i < 4; i++) {
        int kk = ty + i * 8;
        tile[kk][tx] = src[(size_t)(k0 + kk) * N + n0 + tx];
    }
    __syncthreads();
#pragma unroll
    for (int i = 0; i < 4; i++) {
        int nn = ty + i * 8;
        dst[(size_t)(n0 + nn) * K + k0 + tx] = f2bf(scale * tile[tx][nn]);
    }
}

// ---------------- LayerNorm (+affine), f32 in -> bf16 out ----------------
__global__ void ln_kernel(const float* __restrict__ x, u16* __restrict__ out,
                          const float* __restrict__ gammas, const float* __restrict__ betas,
                          int gi) {
    int row = blockIdx.x;
    int t = threadIdx.x;                 // 256 threads
    const float* xr = x + (size_t)row * DIM;
    float v0 = xr[t], v1 = xr[t + 256];
    __shared__ float rs[256], rq[256];
    rs[t] = v0 + v1;
    rq[t] = v0 * v0 + v1 * v1;
    __syncthreads();
    for (int o = 128; o > 0; o >>= 1) {
        if (t < o) { rs[t] += rs[t + o]; rq[t] += rq[t + o]; }
        __syncthreads();
    }
    float mean = rs[0] / DIM;
    float var  = rq[0] / DIM - mean * mean;
    float rstd = rsqrtf(var + 1e-5f);
    float g = gammas[gi], b = betas[gi];
    out[(size_t)row * DIM + t]       = f2bf(g * ((v0 - mean) * rstd) + b);
    out[(size_t)row * DIM + t + 256] = f2bf(g * ((v1 - mean) * rstd) + b);
}

// ---------------- bf16 MFMA GEMM: C(M,N) = A(M,K) @ WT(N,K)^T ----------------
// MF = m-fragments per wave (BM = MF*64). Double-buffered LDS, async staging.
constexpr int FLAG_BF16 = 1, FLAG_GELU = 2, FLAG_SPLIT = 4;

template<int MF>
__global__ __launch_bounds__(256) void gemm_bf16(
    const u16* __restrict__ A, const u16* __restrict__ WT,
    const float* __restrict__ bias, const float* __restrict__ resid,
    void* __restrict__ Cq, void* __restrict__ Ck, void* __restrict__ Cv,
    int M, int N, int K, int flags)
{
    constexpr int BM = MF * 64;
    __shared__ __align__(16) u16 At[2][BM * 64];   // [buf][row][k] swizzled image
    __shared__ __align__(16) u16 Bt[2][64 * 64];   // [buf][n][k]  swizzled image
    const int t = threadIdx.x, lane = t & 63, w = t >> 6;
    const int n0 = blockIdx.x * 64, m0 = blockIdx.y * BM;
    const int l15 = lane & 15, l4 = lane >> 4;

    f32x4 acc[MF][4];
#pragma unroll
    for (int m = 0; m < MF; m++)
#pragma unroll
        for (int n = 0; n < 4; n++) acc[m][n] = (f32x4){0.f, 0.f, 0.f, 0.f};

    auto stage = [&](int buf, int k0) {
#pragma unroll
        for (int i = 0; i < MF * 2; i++) {
            int c = (w * MF * 2 + i) * 64 + lane;
            int r = c >> 3, j = (c & 7) ^ (r & 7);
            gload_lds16(A + (size_t)(m0 + r) * K + k0 + j * 8,
                        (char*)At[buf] + (w * MF * 2 + i) * 1024);
        }
#pragma unroll
        for (int i = 0; i < 2; i++) {
            int c = (w * 2 + i) * 64 + lane;
            int r = c >> 3, j = (c & 7) ^ (r & 7);
            gload_lds16(WT + (size_t)(n0 + r) * K + k0 + j * 8,
                        (char*)Bt[buf] + (w * 2 + i) * 1024);
        }
    };

    const int NT = K / 64;
    stage(0, 0);
    for (int ti = 0; ti < NT; ti++) {
        const int cur = ti & 1;
        asm volatile("s_waitcnt vmcnt(0)" ::: "memory");
        __syncthreads();                         // buf[cur] ready; prev compute done
        if (ti + 1 < NT) stage(cur ^ 1, (ti + 1) * 64);
        __builtin_amdgcn_s_setprio(1);
#pragma unroll
        for (int kk = 0; kk < 2; kk++) {
            bf16x8 af[MF], bfr[4];
#pragma unroll
            for (int m = 0; m < MF; m++) {
                int row = w * MF * 16 + m * 16 + l15;
                af[m] = *(bf16x8*)((char*)At[cur] + row * 128 +
                                   ((kk * 64 + l4 * 16) ^ ((row & 7) << 4)));
            }
#pragma unroll
            for (int n = 0; n < 4; n++) {
                int row = n * 16 + l15;
                bfr[n] = *(bf16x8*)((char*)Bt[cur] + row * 128 +
                                    ((kk * 64 + l4 * 16) ^ ((row & 7) << 4)));
            }
#pragma unroll
            for (int m = 0; m < MF; m++)
#pragma unroll
                for (int n = 0; n < 4; n++)
                    acc[m][n] = __builtin_amdgcn_mfma_f32_16x16x32_bf16(
                        af[m], bfr[n], acc[m][n], 0, 0, 0);
        }
        __builtin_amdgcn_s_setprio(0);
    }

    // epilogue
    const int which = n0 >> 9;        // split: which of q/k/v
    const int nloc0 = n0 & 511;
#pragma unroll
    for (int m = 0; m < MF; m++)
#pragma unroll
        for (int rr = 0; rr < 4; rr++) {
            int row = m0 + w * MF * 16 + m * 16 + l4 * 4 + rr;
#pragma unroll
            for (int n = 0; n < 4; n++) {
                int colg = n0 + n * 16 + l15;
                float cv = acc[m][n][rr];
                if (bias) cv += bias[colg];
                if (flags & FLAG_GELU) cv = 0.5f * cv * (1.0f + erff(cv * 0.70710678118f));
                if (resid) cv += resid[(size_t)row * N + colg];
                if (flags & FLAG_SPLIT) {
                    u16* dst = which == 0 ? (u16*)Cq : which == 1 ? (u16*)Ck : (u16*)Cv;
                    dst[(size_t)row * 512 + nloc0 + n * 16 + l15] = f2bf(cv);
                } else if (flags & FLAG_BF16) {
                    ((u16*)Cq)[(size_t)row * N + colg] = f2bf(cv);
                } else {
                    ((float*)Cq)[(size_t)row * N + colg] = cv;
                }
            }
        }
}

// ---------------- RoPE (in-place on bf16 q and k) ----------------
__global__ void rope_kernel(u16* __restrict__ q, u16* __restrict__ k) {
    int idx = blockIdx.x * blockDim.x + threadIdx.x;   // SEQ*NH*16
    if (idx >= SEQ * NH * 16) return;
    int i = idx & 15;
    int h = (idx >> 4) & (NH - 1);
    int s = idx >> 7;
    float invf = expf(-(2.0f * i / 32.0f) * logf(10000.0f));
    float freq = (float)s * invf;
    float c = cosf(freq), sn = sinf(freq);
    size_t base = (size_t)s * DIM + h * HDIM + 2 * i;
    unsigned int uq = *(unsigned int*)(q + base);
    float x1 = bf2f((u16)(uq & 0xffff)), x2 = bf2f((u16)(uq >> 16));
    *(unsigned int*)(q + base) = cvtpk(x1 * c - x2 * sn, x2 * c + x1 * sn);
    unsigned int uk = *(unsigned int*)(k + base);
    x1 = bf2f((u16)(uk & 0xffff)); x2 = bf2f((u16)(uk >> 16));
    *(unsigned int*)(k + base) = cvtpk(x1 * c - x2 * sn, x2 * c + x1 * sn);
}

// ---------------- per-head transpose: src (S, NH*HD) bf16 -> dst (NH, HD, S) bf16 ----------------
__global__ void transpose_hd(const u16* __restrict__ src, u16* __restrict__ dst) {
    __shared__ __align__(16) u16 tile[64][80];
    int h = blockIdx.y;
    int s0 = blockIdx.x * 64;
    int t = threadIdx.x;               // 256
#pragma unroll
    for (int p = 0; p < 2; p++) {
        int c = p * 256 + t;
        int r = c >> 3, j = c & 7;
        u16x8 v = *(const u16x8*)(src + (size_t)(s0 + r) * DIM + h * HDIM + j * 8);
        *(u16x8*)&tile[r][j * 8] = v;
    }
    __syncthreads();
#pragma unroll
    for (int p = 0; p < 2; p++) {
        int c = p * 256 + t;
        int d = c >> 3, j = c & 7;
        u16x8 v;
#pragma unroll
        for (int i = 0; i < 8; i++) v[i] = tile[j * 8 + i][d];
        *(u16x8*)(dst + ((size_t)h * HDIM + d) * SEQ + s0 + j * 8) = v;
    }
}

// ---------------- flash attention, swapped-QK^T, static-shift exp2 softmax ----------------
// grid (NH, SEQ/64), 256 threads = 4 waves, 16 q-rows/wave.
// S^T = mfma(A=K, B=Q): lane holds 16 scores of ONE q-row (l&15).
// P = exp2(S + mask2)  (no running max: scores are O(0.2), static shift is exact).
// O^T = mfma(A=V^T, B=P); per-lane lrun, reduced once in the epilogue.
__global__ __launch_bounds__(256) void fattn_kernel(
    const u16* __restrict__ q, const u16* __restrict__ k,
    const u16* __restrict__ vT, const float* __restrict__ maskf,
    u16* __restrict__ out)
{
    __shared__ __align__(16) u16 k_s[2][64 * 64];     // [buf][key][d] swizzled image
    __shared__ __align__(16) u16 vt_s[2][64 * 64];    // [buf][d][key] swizzled image
    __shared__ __align__(16) u16 p_s[4][16 * 64];     // per-wave [q][key] swizzled

    const int t = threadIdx.x;
    const int lane = t & 63;
    const int w = t >> 6;
    const int h = blockIdx.x;
    const int q0 = blockIdx.y * 64;
    const int l15 = lane & 15, g = lane >> 4;

    // Q as B-frag, straight from global: q-row = q0+w*16+l15, d = g*8+j (+32)
    const u16* qrow = q + (size_t)(q0 + w * 16 + l15) * DIM + h * HDIM;
    bf16x8 qf0 = *(const bf16x8*)(qrow + g * 8);
    bf16x8 qf1 = *(const bf16x8*)(qrow + g * 8 + 32);

    f32x4 O[4];                       // O^T: [dt], reg r -> d = dt*16+4g+r, col q = l15
#pragma unroll
    for (int dt = 0; dt < 4; dt++) O[dt] = (f32x4){0.f, 0.f, 0.f, 0.f};
    float lrun = 0.f;                 // per-lane partial row sum

    char* pbase = (char*)p_s[w];
    const int psw = (l15 & 7) << 4;

    auto stage = [&](int buf, int kb2) {
#pragma unroll
        for (int i = 0; i < 2; i++) {
            int c = (w * 2 + i) * 64 + lane;
            int r = c >> 3, j = (c & 7) ^ (r & 7);
            gload_lds16(k + (size_t)(kb2 + r) * DIM + h * HDIM + j * 8,
                        (char*)k_s + buf * 8192 + (w * 2 + i) * 1024);
            gload_lds16(vT + ((size_t)h * HDIM + r) * SEQ + kb2 + j * 8,
                        (char*)vt_s + buf * 8192 + (w * 2 + i) * 1024);
        }
    };

    stage(0, 0);
    for (int ti = 0; ti < SEQ / 64; ti++) {
        const int cur = ti & 1;
        const int kb = ti * 64;
        asm volatile("s_waitcnt vmcnt(0)" ::: "memory");
        __syncthreads();                       // buf[cur] ready on all waves
        if (ti + 1 < SEQ / 64) stage(cur ^ 1, kb + 64);

        char* kcur = (char*)k_s + cur * 8192;
        char* vcur = (char*)vt_s + cur * 8192;

        // ---- QK^T (swapped): sacc[kt] rows = keys kt*16+4g+r, col q = l15 ----
        f32x4 sacc[4];
        __builtin_amdgcn_s_setprio(1);
#pragma unroll
        for (int kt = 0; kt < 4; kt++) {
            sacc[kt] = (f32x4){0.f, 0.f, 0.f, 0.f};
            int key = kt * 16 + l15;
            int ksw = (key & 7) << 4;
            char* kbase = kcur + key * 128;
            bf16x8 a0 = *(bf16x8*)(kbase + ((g * 16)      ^ ksw));
            bf16x8 a1 = *(bf16x8*)(kbase + ((g * 16 + 64) ^ ksw));
            sacc[kt] = __builtin_amdgcn_mfma_f32_16x16x32_bf16(a0, qf0, sacc[kt], 0, 0, 0);
            sacc[kt] = __builtin_amdgcn_mfma_f32_16x16x32_bf16(a1, qf1, sacc[kt], 0, 0, 0);
        }
        __builtin_amdgcn_s_setprio(0);

        // ---- P = exp2(S + mask2); accumulate per-lane lrun; pack to LDS ----
#pragma unroll
        for (int kt = 0; kt < 4; kt++) {
            float4 mf = *(const float4*)(maskf + kb + kt * 16 + g * 4);
            float p0 = EXP2F(sacc[kt][0] + mf.x);
            float p1 = EXP2F(sacc[kt][1] + mf.y);
            float p2 = EXP2F(sacc[kt][2] + mf.z);
            float p3 = EXP2F(sacc[kt][3] + mf.w);
            lrun += (p0 + p1) + (p2 + p3);
            unsigned int pk0 = cvtpk(p0, p1);
            unsigned int pk1 = cvtpk(p2, p3);
            int col = (kt * 16 + g * 4) * 2;               // byte col
            *(unsigned int*)(pbase + l15 * 128 + ((col    ) ^ psw)) = pk0;
            *(unsigned int*)(pbase + l15 * 128 + ((col + 4) ^ psw)) = pk1;
        }

        // ---- PV: O^T += V^T(A) @ P(B) ----
        __builtin_amdgcn_s_setprio(1);
#pragma unroll
        for (int h2 = 0; h2 < 2; h2++) {
            bf16x8 pb = *(bf16x8*)(pbase + l15 * 128 + (((h2 * 4 + g) * 16) ^ psw));
#pragma unroll
            for (int dt = 0; dt < 4; dt++) {
                int d = dt * 16 + l15;
                bf16x8 va = *(bf16x8*)(vcur + d * 128 + (((h2 * 4 + g) * 16) ^ ((d & 7) << 4)));
                O[dt] = __builtin_amdgcn_mfma_f32_16x16x32_bf16(va, pb, O[dt], 0, 0, 0);
            }
        }
        __builtin_amdgcn_s_setprio(0);
    }

    // ---- epilogue: reduce lrun across the 4 lanes sharing a q-row, scale, store ----
    lrun += __shfl_xor(lrun, 16, 64);
    lrun += __shfl_xor(lrun, 32, 64);
    float inv = 1.0f / lrun;
    u16* orow = out + (size_t)(q0 + w * 16 + l15) * DIM + h * HDIM;
#pragma unroll
    for (int dt = 0; dt < 4; dt++)
#pragma unroll
        for (int r = 0; r < 4; r += 2) {
            unsigned int pk = cvtpk(O[dt][r] * inv, O[dt][r + 1] * inv);
            *(unsigned int*)(orow + dt * 16 + 4 * g + r) = pk;
        }
}

extern "C" void kernel_launch(void* const* d_in, const int* in_sizes, int n_in,
                              void* d_out, int out_size, void* d_ws, size_t ws_size,
                              hipStream_t stream) {
    const float* x      = (const float*)d_in[0];
    const float* gammas = (const float*)d_in[1];
    const float* betas  = (const float*)d_in[2];
    const float* wq     = (const float*)d_in[3];
    const float* wk     = (const float*)d_in[4];
    const float* wv     = (const float*)d_in[5];
    const float* wo     = (const float*)d_in[6];
    const float* bo     = (const float*)d_in[7];
    const float* w1     = (const float*)d_in[8];
    const float* b1     = (const float*)d_in[9];
    const float* w2     = (const float*)d_in[10];
    const float* b2     = (const float*)d_in[11];
    const int*   mask   = (const int*)d_in[12];
    float* out = (float*)d_out;

    // ---- workspace layout (bytes) ----
    char* wsb = (char*)d_ws;
    u16*   h1b   = (u16*)(wsb + 0);                       // 4 MB; attn-out; part of f1b
    u16*   kb    = (u16*)(wsb + (4ull  << 20));           // 4 MB; part of f1b
    u16*   vb    = (u16*)(wsb + (8ull  << 20));           // 4 MB; part of f1b
    u16*   vTb   = (u16*)(wsb + (12ull << 20));           // 4 MB; part of f1b
    u16*   qb    = (u16*)(wsb + (16ull << 20));           // 4 MB; reused as h2b
    float* x2    = (float*)(wsb + (20ull << 20));         // 8 MB
    u16*   wqkvT = (u16*)(wsb + (28ull << 20));           // 1.5 MB
    u16*   woT   = wqkvT + 1536 * 512;                    // 0.5 MB
    u16*   w1T   = woT   + 512 * 512;                     // 2 MB
    u16*   w2T   = w1T   + 2048 * 512;                    // 2 MB
    float* maskf = (float*)(wsb + (34ull << 20));         // 16 KB
    u16*   f1b   = h1b;
    u16*   h2b   = qb;
    u16*   attnb = h1b;

    // 0. mask + weight prep (exp2-domain scale folded into wq)
    maskf_kernel<<<SEQ / 256, 256, 0, stream>>>(mask, maskf);
    wconv<<<dim3(DIM / 32, DIM / 32), 256, 0, stream>>>(wq, wqkvT, DIM, DIM, QSCALE);
    wconv<<<dim3(DIM / 32, DIM / 32), 256, 0, stream>>>(wk, wqkvT + 512 * 512, DIM, DIM, 1.f);
    wconv<<<dim3(DIM / 32, DIM / 32), 256, 0, stream>>>(wv, wqkvT + 1024 * 512, DIM, DIM, 1.f);
    wconv<<<dim3(DIM / 32, DIM / 32), 256, 0, stream>>>(wo, woT, DIM, DIM, 1.f);
    wconv<<<dim3(FFD / 32, DIM / 32), 256, 0, stream>>>(w1, w1T, DIM, FFD, 1.f);
    wconv<<<dim3(DIM / 32, FFD / 32), 256, 0, stream>>>(w2, w2T, FFD, DIM, 1.f);

    // 1. h1 = LN(x) (bf16)
    ln_kernel<<<SEQ, 256, 0, stream>>>(x, h1b, gammas, betas, 0);
    // 2. fused QKV projection (q pre-scaled by log2e/8)
    gemm_bf16<2><<<dim3(1536 / 64, SEQ / 128), 256, 0, stream>>>(
        h1b, wqkvT, nullptr, nullptr, qb, kb, vb, SEQ, 1536, DIM, FLAG_SPLIT | FLAG_BF16);
    // 3. RoPE in-place on q,k (rotation commutes with scalar scale)
    rope_kernel<<<(SEQ * NH * 16) / 256, 256, 0, stream>>>(qb, kb);
    // 4. vT = per-head transpose of v
    transpose_hd<<<dim3(SEQ / 64, NH), 256, 0, stream>>>(vb, vTb);
    // 5. attention
    fattn_kernel<<<dim3(NH, SEQ / 64), 256, 0, stream>>>(qb, kb, vTb, maskf, attnb);
    // 6. x2 = x + attn@wo + bo (f32)  [BM=64: 512 blocks, 2/CU]
    gemm_bf16<1><<<dim3(DIM / 64, SEQ / 64), 256, 0, stream>>>(
        attnb, woT, bo, x, x2, nullptr, nullptr, SEQ, DIM, DIM, 0);
    // 7. h2 = LN(x2) (bf16)
    ln_kernel<<<SEQ, 256, 0, stream>>>(x2, h2b, gammas, betas, 1);
    // 8. f1 = gelu(h2@w1 + b1) (bf16)
    gemm_bf16<2><<<dim3(FFD / 64, SEQ / 128), 256, 0, stream>>>(
        h2b, w1T, b1, nullptr, f1b, nullptr, nullptr, SEQ, FFD, DIM, FLAG_BF16 | FLAG_GELU);
    // 9. out = x2 + f1@w2 + b2 (f32)  [BM=64]
    gemm_bf16<1><<<dim3(DIM / 64, SEQ / 64), 256, 0, stream>>>(
        f1b, w2T, b2, x2, out, nullptr, nullptr, SEQ, DIM, FFD, 0);
}

// Round 6
// 196.604 us; speedup vs baseline: 9.4137x; 1.2129x over previous
//
#include <hip/hip_runtime.h>
#include <math.h>

constexpr int SEQ  = 4096;
constexpr int DIM  = 512;
constexpr int NH   = 8;
constexpr int HDIM = 64;
constexpr int FFD  = 2048;
constexpr int KSPLIT = 2;
constexpr int KHALF  = SEQ / KSPLIT;

typedef unsigned short u16;
typedef __attribute__((ext_vector_type(8))) short bf16x8;
typedef __attribute__((ext_vector_type(4))) float f32x4;
typedef __attribute__((ext_vector_type(8))) unsigned short u16x8;

// score scale: (1/8) * log2(e), folded into wq. Softmax computed in exp2 domain
// with static shift 8 (scores are O(0.2); softmax is shift/base invariant).
#define LOG2E      1.4426950408889634f
#define QSCALE     (0.125f * LOG2E)
#define MASK_ON    (-8.0f * LOG2E)        // unmasked: 2^(s*log2e - 8*log2e) = e^(s-8)
#define MASK_OFF   (-1.4427e9f)           // masked: exp2 underflows to exact 0

static __device__ __forceinline__ u16 f2bf(float x) {
    union { float f; unsigned int u; } v; v.f = x;
    unsigned int r = v.u + 0x7fff + ((v.u >> 16) & 1);
    return (u16)(r >> 16);
}
static __device__ __forceinline__ float bf2f(u16 h) {
    union { unsigned int u; float f; } v; v.u = ((unsigned int)h) << 16;
    return v.f;
}
static __device__ __forceinline__ unsigned int cvtpk(float lo, float hi) {
    unsigned int r;
    asm volatile("v_cvt_pk_bf16_f32 %0, %1, %2" : "=v"(r) : "v"(lo), "v"(hi));
    return r;
}
static __device__ __forceinline__ float exp2f_fast(float x) {
    float r; asm volatile("v_exp_f32 %0, %1" : "=v"(r) : "v"(x)); return r;
}
static __device__ __forceinline__ void gload_lds16(const void* g, void* l) {
    __builtin_amdgcn_global_load_lds(
        (const __attribute__((address_space(1))) unsigned int*)g,
        (__attribute__((address_space(3))) unsigned int*)l, 16, 0, 0);
}

// ---------------- fused prep: mask + all weight converts (1 dispatch) ----------------
__global__ void prep_kernel(const float* __restrict__ wq, const float* __restrict__ wk,
                            const float* __restrict__ wv, const float* __restrict__ wo,
                            const float* __restrict__ w1, const float* __restrict__ w2,
                            u16* __restrict__ wqkvT, u16* __restrict__ woT,
                            u16* __restrict__ w1T, u16* __restrict__ w2T,
                            const int* __restrict__ mask, float* __restrict__ mf) {
    int b = blockIdx.x;
    if (b < 16) {                               // mask section
        int i = b * 256 + threadIdx.x;
        mf[i] = mask[i] ? MASK_ON : MASK_OFF;
        return;
    }
    b -= 16;
    const float* src; u16* dst; int K, N; float scale = 1.f;
    if (b < 256)       { src = wq; dst = wqkvT;            K = 512;  N = 512; scale = QSCALE; }
    else if (b < 512)  { src = wk; dst = wqkvT + 512*512;  K = 512;  N = 512; b -= 256; }
    else if (b < 768)  { src = wv; dst = wqkvT + 1024*512; K = 512;  N = 512; b -= 512; }
    else if (b < 1024) { src = wo; dst = woT;              K = 512;  N = 512; b -= 768; }
    else if (b < 2048) { src = w1; dst = w1T;              K = 512;  N = 2048; b -= 1024; }
    else               { src = w2; dst = w2T;              K = 2048; N = 512;  b -= 2048; }
    __shared__ float tile[32][33];
    int tiles_x = N / 32;
    int n0 = (b % tiles_x) * 32, k0 = (b / tiles_x) * 32;
    int tx = threadIdx.x & 31, ty = threadIdx.x >> 5;   // 32 x 8
#pragma unroll
    for (int i = 0; i < 4; i++) {
        int kk = ty + i * 8;
        tile[kk][tx] = src[(size_t)(k0 + kk) * N + n0 + tx];
    }
    __syncthreads();
#pragma unroll
    for (int i = 0; i < 4; i++) {
        int nn = ty + i * 8;
        dst[(size_t)(n0 + nn) * K + k0 + tx] = f2bf(scale * tile[tx][nn]);
    }
}

// ---------------- LayerNorm (+affine), f32 in -> bf16 out ----------------
__global__ void ln_kernel(const float* __restrict__ x, u16* __restrict__ out,
                          const float* __restrict__ gammas, const float* __restrict__ betas,
                          int gi) {
    int row = blockIdx.x;
    int t = threadIdx.x;                 // 256 threads
    const float* xr = x + (size_t)row * DIM;
    float v0 = xr[t], v1 = xr[t + 256];
    __shared__ float rs[256], rq[256];
    rs[t] = v0 + v1;
    rq[t] = v0 * v0 + v1 * v1;
    __syncthreads();
    for (int o = 128; o > 0; o >>= 1) {
        if (t < o) { rs[t] += rs[t + o]; rq[t] += rq[t + o]; }
        __syncthreads();
    }
    float mean = rs[0] / DIM;
    float var  = rq[0] / DIM - mean * mean;
    float rstd = rsqrtf(var + 1e-5f);
    float g = gammas[gi], b = betas[gi];
    out[(size_t)row * DIM + t]       = f2bf(g * ((v0 - mean) * rstd) + b);
    out[(size_t)row * DIM + t + 256] = f2bf(g * ((v1 - mean) * rstd) + b);
}

// ---------------- bf16 MFMA GEMM: C(M,N) = A(M,K) @ WT(N,K)^T ----------------
constexpr int FLAG_BF16 = 1, FLAG_GELU = 2, FLAG_SPLIT = 4;

template<int MF>
__global__ __launch_bounds__(256) void gemm_bf16(
    const u16* __restrict__ A, const u16* __restrict__ WT,
    const float* __restrict__ bias, const float* __restrict__ resid,
    void* __restrict__ Cq, void* __restrict__ Ck, void* __restrict__ Cv,
    int M, int N, int K, int flags)
{
    constexpr int BM = MF * 64;
    __shared__ __align__(16) u16 At[2][BM * 64];   // [buf][row][k] swizzled image
    __shared__ __align__(16) u16 Bt[2][64 * 64];   // [buf][n][k]  swizzled image
    const int t = threadIdx.x, lane = t & 63, w = t >> 6;
    const int n0 = blockIdx.x * 64, m0 = blockIdx.y * BM;
    const int l15 = lane & 15, l4 = lane >> 4;

    f32x4 acc[MF][4];
#pragma unroll
    for (int m = 0; m < MF; m++)
#pragma unroll
        for (int n = 0; n < 4; n++) acc[m][n] = (f32x4){0.f, 0.f, 0.f, 0.f};

    auto stage = [&](int buf, int k0) {
#pragma unroll
        for (int i = 0; i < MF * 2; i++) {
            int c = (w * MF * 2 + i) * 64 + lane;
            int r = c >> 3, j = (c & 7) ^ (r & 7);
            gload_lds16(A + (size_t)(m0 + r) * K + k0 + j * 8,
                        (char*)At[buf] + (w * MF * 2 + i) * 1024);
        }
#pragma unroll
        for (int i = 0; i < 2; i++) {
            int c = (w * 2 + i) * 64 + lane;
            int r = c >> 3, j = (c & 7) ^ (r & 7);
            gload_lds16(WT + (size_t)(n0 + r) * K + k0 + j * 8,
                        (char*)Bt[buf] + (w * 2 + i) * 1024);
        }
    };

    const int NT = K / 64;
    stage(0, 0);
    for (int ti = 0; ti < NT; ti++) {
        const int cur = ti & 1;
        asm volatile("s_waitcnt vmcnt(0)" ::: "memory");
        __syncthreads();                         // buf[cur] ready; prev compute done
        if (ti + 1 < NT) stage(cur ^ 1, (ti + 1) * 64);
        __builtin_amdgcn_s_setprio(1);
#pragma unroll
        for (int kk = 0; kk < 2; kk++) {
            bf16x8 af[MF], bfr[4];
#pragma unroll
            for (int m = 0; m < MF; m++) {
                int row = w * MF * 16 + m * 16 + l15;
                af[m] = *(bf16x8*)((char*)At[cur] + row * 128 +
                                   ((kk * 64 + l4 * 16) ^ ((row & 7) << 4)));
            }
#pragma unroll
            for (int n = 0; n < 4; n++) {
                int row = n * 16 + l15;
                bfr[n] = *(bf16x8*)((char*)Bt[cur] + row * 128 +
                                    ((kk * 64 + l4 * 16) ^ ((row & 7) << 4)));
            }
#pragma unroll
            for (int m = 0; m < MF; m++)
#pragma unroll
                for (int n = 0; n < 4; n++)
                    acc[m][n] = __builtin_amdgcn_mfma_f32_16x16x32_bf16(
                        af[m], bfr[n], acc[m][n], 0, 0, 0);
        }
        __builtin_amdgcn_s_setprio(0);
    }

    // epilogue
    const int which = n0 >> 9;        // split: which of q/k/v
    const int nloc0 = n0 & 511;
#pragma unroll
    for (int m = 0; m < MF; m++)
#pragma unroll
        for (int rr = 0; rr < 4; rr++) {
            int row = m0 + w * MF * 16 + m * 16 + l4 * 4 + rr;
#pragma unroll
            for (int n = 0; n < 4; n++) {
                int colg = n0 + n * 16 + l15;
                float cv = acc[m][n][rr];
                if (bias) cv += bias[colg];
                if (flags & FLAG_GELU) cv = 0.5f * cv * (1.0f + erff(cv * 0.70710678118f));
                if (resid) cv += resid[(size_t)row * N + colg];
                if (flags & FLAG_SPLIT) {
                    u16* dst = which == 0 ? (u16*)Cq : which == 1 ? (u16*)Ck : (u16*)Cv;
                    dst[(size_t)row * 512 + nloc0 + n * 16 + l15] = f2bf(cv);
                } else if (flags & FLAG_BF16) {
                    ((u16*)Cq)[(size_t)row * N + colg] = f2bf(cv);
                } else {
                    ((float*)Cq)[(size_t)row * N + colg] = cv;
                }
            }
        }
}

// ---------------- RoPE (in-place on bf16 q and k) ----------------
__global__ void rope_kernel(u16* __restrict__ q, u16* __restrict__ k) {
    int idx = blockIdx.x * blockDim.x + threadIdx.x;   // SEQ*NH*16
    if (idx >= SEQ * NH * 16) return;
    int i = idx & 15;
    int h = (idx >> 4) & (NH - 1);
    int s = idx >> 7;
    float invf = expf(-(2.0f * i / 32.0f) * logf(10000.0f));
    float freq = (float)s * invf;
    float c = cosf(freq), sn = sinf(freq);
    size_t base = (size_t)s * DIM + h * HDIM + 2 * i;
    unsigned int uq = *(unsigned int*)(q + base);
    float x1 = bf2f((u16)(uq & 0xffff)), x2 = bf2f((u16)(uq >> 16));
    *(unsigned int*)(q + base) = cvtpk(x1 * c - x2 * sn, x2 * c + x1 * sn);
    unsigned int uk = *(unsigned int*)(k + base);
    x1 = bf2f((u16)(uk & 0xffff)); x2 = bf2f((u16)(uk >> 16));
    *(unsigned int*)(k + base) = cvtpk(x1 * c - x2 * sn, x2 * c + x1 * sn);
}

// ---------------- per-head transpose: src (S, NH*HD) bf16 -> dst (NH, HD, S) bf16 ----------------
__global__ void transpose_hd(const u16* __restrict__ src, u16* __restrict__ dst) {
    __shared__ __align__(16) u16 tile[64][80];
    int h = blockIdx.y;
    int s0 = blockIdx.x * 64;
    int t = threadIdx.x;               // 256
#pragma unroll
    for (int p = 0; p < 2; p++) {
        int c = p * 256 + t;
        int r = c >> 3, j = c & 7;
        u16x8 v = *(const u16x8*)(src + (size_t)(s0 + r) * DIM + h * HDIM + j * 8);
        *(u16x8*)&tile[r][j * 8] = v;
    }
    __syncthreads();
#pragma unroll
    for (int p = 0; p < 2; p++) {
        int c = p * 256 + t;
        int d = c >> 3, j = c & 7;
        u16x8 v;
#pragma unroll
        for (int i = 0; i < 8; i++) v[i] = tile[j * 8 + i][d];
        *(u16x8*)(dst + ((size_t)h * HDIM + d) * SEQ + s0 + j * 8) = v;
    }
}

// ---------------- flash attention, KV-split, swapped-QK^T, static-shift exp2 ----------------
// grid (NH, SEQ/64, KSPLIT), 256 threads = 4 waves, 16 q-rows/wave.
// Each split handles KHALF keys, writes UNNORMALIZED bf16 O-partial + row-sum partial.
// Static shift => partials combine by simple addition (no max merge).
__global__ __launch_bounds__(256) void fattn_kernel(
    const u16* __restrict__ q, const u16* __restrict__ k,
    const u16* __restrict__ vT, const float* __restrict__ maskf,
    u16* __restrict__ Opart, float* __restrict__ lpart)
{
    __shared__ __align__(16) u16 k_s[2][64 * 64];     // [buf][key][d] swizzled image
    __shared__ __align__(16) u16 vt_s[2][64 * 64];    // [buf][d][key] swizzled image
    __shared__ __align__(16) u16 p_s[4][16 * 64];     // per-wave [q][key] swizzled

    const int t = threadIdx.x;
    const int lane = t & 63;
    const int w = t >> 6;
    const int h = blockIdx.x;
    const int q0 = blockIdx.y * 64;
    const int split = blockIdx.z;
    const int kb0 = split * KHALF;
    const int l15 = lane & 15, g = lane >> 4;

    // Q as B-frag, straight from global: q-row = q0+w*16+l15, d = g*8+j (+32)
    const u16* qrow = q + (size_t)(q0 + w * 16 + l15) * DIM + h * HDIM;
    bf16x8 qf0 = *(const bf16x8*)(qrow + g * 8);
    bf16x8 qf1 = *(const bf16x8*)(qrow + g * 8 + 32);

    f32x4 O[4];                       // O^T: [dt], reg r -> d = dt*16+4g+r, col q = l15
#pragma unroll
    for (int dt = 0; dt < 4; dt++) O[dt] = (f32x4){0.f, 0.f, 0.f, 0.f};
    float lrun = 0.f;                 // per-lane partial row sum

    char* pbase = (char*)p_s[w];
    const int psw = (l15 & 7) << 4;

    auto stage = [&](int buf, int kb2) {
#pragma unroll
        for (int i = 0; i < 2; i++) {
            int c = (w * 2 + i) * 64 + lane;
            int r = c >> 3, j = (c & 7) ^ (r & 7);
            gload_lds16(k + (size_t)(kb2 + r) * DIM + h * HDIM + j * 8,
                        (char*)k_s + buf * 8192 + (w * 2 + i) * 1024);
            gload_lds16(vT + ((size_t)h * HDIM + r) * SEQ + kb2 + j * 8,
                        (char*)vt_s + buf * 8192 + (w * 2 + i) * 1024);
        }
    };

    stage(0, kb0);
    for (int ti = 0; ti < KHALF / 64; ti++) {
        const int cur = ti & 1;
        const int kb = kb0 + ti * 64;
        asm volatile("s_waitcnt vmcnt(0)" ::: "memory");
        __syncthreads();                       // buf[cur] ready on all waves
        if (ti + 1 < KHALF / 64) stage(cur ^ 1, kb + 64);

        char* kcur = (char*)k_s + cur * 8192;
        char* vcur = (char*)vt_s + cur * 8192;

        // ---- QK^T (swapped): sacc[kt] rows = keys kt*16+4g+r, col q = l15 ----
        f32x4 sacc[4];
        __builtin_amdgcn_s_setprio(1);
#pragma unroll
        for (int kt = 0; kt < 4; kt++) {
            sacc[kt] = (f32x4){0.f, 0.f, 0.f, 0.f};
            int key = kt * 16 + l15;
            int ksw = (key & 7) << 4;
            char* kbase = kcur + key * 128;
            bf16x8 a0 = *(bf16x8*)(kbase + ((g * 16)      ^ ksw));
            bf16x8 a1 = *(bf16x8*)(kbase + ((g * 16 + 64) ^ ksw));
            sacc[kt] = __builtin_amdgcn_mfma_f32_16x16x32_bf16(a0, qf0, sacc[kt], 0, 0, 0);
            sacc[kt] = __builtin_amdgcn_mfma_f32_16x16x32_bf16(a1, qf1, sacc[kt], 0, 0, 0);
        }
        __builtin_amdgcn_s_setprio(0);

        // ---- P = exp2(S + mask2); accumulate per-lane lrun; pack to LDS ----
#pragma unroll
        for (int kt = 0; kt < 4; kt++) {
            float4 mf = *(const float4*)(maskf + kb + kt * 16 + g * 4);
            float p0 = exp2f_fast(sacc[kt][0] + mf.x);
            float p1 = exp2f_fast(sacc[kt][1] + mf.y);
            float p2 = exp2f_fast(sacc[kt][2] + mf.z);
            float p3 = exp2f_fast(sacc[kt][3] + mf.w);
            lrun += (p0 + p1) + (p2 + p3);
            unsigned int pk0 = cvtpk(p0, p1);
            unsigned int pk1 = cvtpk(p2, p3);
            int col = (kt * 16 + g * 4) * 2;               // byte col
            *(unsigned int*)(pbase + l15 * 128 + ((col    ) ^ psw)) = pk0;
            *(unsigned int*)(pbase + l15 * 128 + ((col + 4) ^ psw)) = pk1;
        }

        // ---- PV: O^T += V^T(A) @ P(B) ----
        __builtin_amdgcn_s_setprio(1);
#pragma unroll
        for (int h2 = 0; h2 < 2; h2++) {
            bf16x8 pb = *(bf16x8*)(pbase + l15 * 128 + (((h2 * 4 + g) * 16) ^ psw));
#pragma unroll
            for (int dt = 0; dt < 4; dt++) {
                int d = dt * 16 + l15;
                bf16x8 va = *(bf16x8*)(vcur + d * 128 + (((h2 * 4 + g) * 16) ^ ((d & 7) << 4)));
                O[dt] = __builtin_amdgcn_mfma_f32_16x16x32_bf16(va, pb, O[dt], 0, 0, 0);
            }
        }
        __builtin_amdgcn_s_setprio(0);
    }

    // ---- epilogue: store UNNORMALIZED partial O (bf16) + partial row sum ----
    lrun += __shfl_xor(lrun, 16, 64);
    lrun += __shfl_xor(lrun, 32, 64);
    u16* orow = Opart + (size_t)split * SEQ * DIM
                      + (size_t)(q0 + w * 16 + l15) * DIM + h * HDIM;
#pragma unroll
    for (int dt = 0; dt < 4; dt++)
#pragma unroll
        for (int r = 0; r < 4; r += 2) {
            unsigned int pk = cvtpk(O[dt][r], O[dt][r + 1]);
            *(unsigned int*)(orow + dt * 16 + 4 * g + r) = pk;
        }
    if (g == 0)
        lpart[((size_t)split * NH + h) * SEQ + q0 + w * 16 + l15] = lrun;
}

// ---------------- combine: out = (Oa + Ob) / (la + lb), bf16 ----------------
__global__ void attn_combine(const u16* __restrict__ Opart, const float* __restrict__ lpart,
                             u16* __restrict__ out) {
    int row = blockIdx.x;
    int t = threadIdx.x;               // 256 threads x 2 cols
    int col = t * 2;
    int h = col >> 6;
    float la = lpart[(size_t)h * SEQ + row];
    float lb = lpart[((size_t)NH + h) * SEQ + row];
    float inv = 1.0f / (la + lb);
    unsigned int ua = *(const unsigned int*)(Opart + (size_t)row * DIM + col);
    unsigned int ub = *(const unsigned int*)(Opart + (size_t)SEQ * DIM + (size_t)row * DIM + col);
    float o0 = bf2f((u16)(ua & 0xffff)) + bf2f((u16)(ub & 0xffff));
    float o1 = bf2f((u16)(ua >> 16))    + bf2f((u16)(ub >> 16));
    *(unsigned int*)(out + (size_t)row * DIM + col) = cvtpk(o0 * inv, o1 * inv);
}

extern "C" void kernel_launch(void* const* d_in, const int* in_sizes, int n_in,
                              void* d_out, int out_size, void* d_ws, size_t ws_size,
                              hipStream_t stream) {
    const float* x      = (const float*)d_in[0];
    const float* gammas = (const float*)d_in[1];
    const float* betas  = (const float*)d_in[2];
    const float* wq     = (const float*)d_in[3];
    const float* wk     = (const float*)d_in[4];
    const float* wv     = (const float*)d_in[5];
    const float* wo     = (const float*)d_in[6];
    const float* bo     = (const float*)d_in[7];
    const float* w1     = (const float*)d_in[8];
    const float* b1     = (const float*)d_in[9];
    const float* w2     = (const float*)d_in[10];
    const float* b2     = (const float*)d_in[11];
    const int*   mask   = (const int*)d_in[12];
    float* out = (float*)d_out;

    // ---- workspace layout (bytes) ----
    char* wsb = (char*)d_ws;
    u16*   h1b   = (u16*)(wsb + 0);                       // 4 MB; attnb; start of f1b
    u16*   kb    = (u16*)(wsb + (4ull  << 20));           // 4 MB
    u16*   vb    = (u16*)(wsb + (8ull  << 20));           // 4 MB; dead after transpose -> lpart
    u16*   vTb   = (u16*)(wsb + (12ull << 20));           // 4 MB
    u16*   qb    = (u16*)(wsb + (16ull << 20));           // 4 MB; reused as h2b
    float* x2    = (float*)(wsb + (20ull << 20));         // 8 MB; Opart during attention
    u16*   wqkvT = (u16*)(wsb + (28ull << 20));           // 1.5 MB
    u16*   woT   = wqkvT + 1536 * 512;                    // 0.5 MB
    u16*   w1T   = woT   + 512 * 512;                     // 2 MB
    u16*   w2T   = w1T   + 2048 * 512;                    // 2 MB
    float* maskf = (float*)(wsb + (34ull << 20));         // 16 KB
    u16*   f1b   = h1b;                                   // 16 MB spanning slots 0-3 (FFN phase)
    u16*   h2b   = qb;
    u16*   attnb = h1b;
    u16*   Opart = (u16*)x2;                              // 8 MB (2 splits x 4 MB), dead x2 region
    float* lpart = (float*)vb;                            // 256 KB, dead vb region

    // 0. fused prep: mask + all weight converts (1 dispatch)
    prep_kernel<<<16 + 3072, 256, 0, stream>>>(wq, wk, wv, wo, w1, w2,
                                               wqkvT, woT, w1T, w2T, mask, maskf);
    // 1. h1 = LN(x) (bf16)
    ln_kernel<<<SEQ, 256, 0, stream>>>(x, h1b, gammas, betas, 0);
    // 2. fused QKV projection (q pre-scaled by log2e/8)
    gemm_bf16<2><<<dim3(1536 / 64, SEQ / 128), 256, 0, stream>>>(
        h1b, wqkvT, nullptr, nullptr, qb, kb, vb, SEQ, 1536, DIM, FLAG_SPLIT | FLAG_BF16);
    // 3. RoPE in-place on q,k (rotation commutes with scalar scale)
    rope_kernel<<<(SEQ * NH * 16) / 256, 256, 0, stream>>>(qb, kb);
    // 4. vT = per-head transpose of v
    transpose_hd<<<dim3(SEQ / 64, NH), 256, 0, stream>>>(vb, vTb);
    // 5. attention, KV-split x2 (partials), then combine
    fattn_kernel<<<dim3(NH, SEQ / 64, KSPLIT), 256, 0, stream>>>(
        qb, kb, vTb, maskf, Opart, lpart);
    attn_combine<<<SEQ, 256, 0, stream>>>(Opart, lpart, attnb);
    // 6. x2 = x + attn@wo + bo (f32)  [overwrites Opart after it's consumed]
    gemm_bf16<1><<<dim3(DIM / 64, SEQ / 64), 256, 0, stream>>>(
        attnb, woT, bo, x, x2, nullptr, nullptr, SEQ, DIM, DIM, 0);
    // 7. h2 = LN(x2) (bf16)
    ln_kernel<<<SEQ, 256, 0, stream>>>(x2, h2b, gammas, betas, 1);
    // 8. f1 = gelu(h2@w1 + b1) (bf16)
    gemm_bf16<2><<<dim3(FFD / 64, SEQ / 128), 256, 0, stream>>>(
        h2b, w1T, b1, nullptr, f1b, nullptr, nullptr, SEQ, FFD, DIM, FLAG_BF16 | FLAG_GELU);
    // 9. out = x2 + f1@w2 + b2 (f32)
    gemm_bf16<1><<<dim3(DIM / 64, SEQ / 64), 256, 0, stream>>>(
        f1b, w2T, b2, x2, out, nullptr, nullptr, SEQ, DIM, FFD, 0);
}

// Round 7
// 182.791 us; speedup vs baseline: 10.1251x; 1.0756x over previous
//
#include <hip/hip_runtime.h>
#include <math.h>

constexpr int SEQ  = 4096;
constexpr int DIM  = 512;
constexpr int NH   = 8;
constexpr int HDIM = 64;
constexpr int FFD  = 2048;
constexpr int KSPLIT = 3;          // tiles 22/21/21 of 64 keys -> grid 768 = 3/CU exact

typedef unsigned short u16;
typedef __attribute__((ext_vector_type(8))) short bf16x8;
typedef __attribute__((ext_vector_type(4))) float f32x4;
typedef __attribute__((ext_vector_type(8))) unsigned short u16x8;

// score scale: (1/8) * log2(e), folded into wq. Softmax computed in exp2 domain
// with static shift 8 (scores are O(0.2); softmax is shift/base invariant).
#define LOG2E      1.4426950408889634f
#define QSCALE     (0.125f * LOG2E)
#define MASK_ON    (-8.0f * LOG2E)
#define MASK_OFF   (-1.4427e9f)

static __device__ __forceinline__ u16 f2bf(float x) {
    union { float f; unsigned int u; } v; v.f = x;
    unsigned int r = v.u + 0x7fff + ((v.u >> 16) & 1);
    return (u16)(r >> 16);
}
static __device__ __forceinline__ float bf2f(u16 h) {
    union { unsigned int u; float f; } v; v.u = ((unsigned int)h) << 16;
    return v.f;
}
static __device__ __forceinline__ unsigned int cvtpk(float lo, float hi) {
    unsigned int r;
    asm volatile("v_cvt_pk_bf16_f32 %0, %1, %2" : "=v"(r) : "v"(lo), "v"(hi));
    return r;
}
static __device__ __forceinline__ float exp2f_fast(float x) {
    float r; asm volatile("v_exp_f32 %0, %1" : "=v"(r) : "v"(x)); return r;
}
static __device__ __forceinline__ void gload_lds16(const void* g, void* l) {
    __builtin_amdgcn_global_load_lds(
        (const __attribute__((address_space(1))) unsigned int*)g,
        (__attribute__((address_space(3))) unsigned int*)l, 16, 0, 0);
}

// ---------------- fused prep: mask + rope tables + all weight converts ----------------
__global__ void prep_kernel(const float* __restrict__ wq, const float* __restrict__ wk,
                            const float* __restrict__ wv, const float* __restrict__ wo,
                            const float* __restrict__ w1, const float* __restrict__ w2,
                            u16* __restrict__ wqkvT, u16* __restrict__ woT,
                            u16* __restrict__ w1T, u16* __restrict__ w2T,
                            const int* __restrict__ mask, float* __restrict__ mf,
                            float* __restrict__ ct, float* __restrict__ st) {
    int b = blockIdx.x;
    if (b < 16) {                               // mask section
        int i = b * 256 + threadIdx.x;
        mf[i] = mask[i] ? MASK_ON : MASK_OFF;
        return;
    }
    b -= 16;
    if (b < 256) {                              // rope cos/sin tables: [s][i], i<16
        int idx = b * 256 + threadIdx.x;        // 65536 = 4096*16
        int s = idx >> 4, i = idx & 15;
        float invf = expf(-(float)i * (9.2103403719761836f / 16.0f));  // 10000^(-i/16)
        float freq = (float)s * invf;
        ct[idx] = cosf(freq);
        st[idx] = sinf(freq);
        return;
    }
    b -= 256;
    const float* src; u16* dst; int K, N; float scale = 1.f;
    if (b < 256)       { src = wq; dst = wqkvT;            K = 512;  N = 512; scale = QSCALE; }
    else if (b < 512)  { src = wk; dst = wqkvT + 512*512;  K = 512;  N = 512; b -= 256; }
    else if (b < 768)  { src = wv; dst = wqkvT + 1024*512; K = 512;  N = 512; b -= 512; }
    else if (b < 1024) { src = wo; dst = woT;              K = 512;  N = 512; b -= 768; }
    else if (b < 2048) { src = w1; dst = w1T;              K = 512;  N = 2048; b -= 1024; }
    else               { src = w2; dst = w2T;              K = 2048; N = 512;  b -= 2048; }
    __shared__ float tile[32][33];
    int tiles_x = N / 32;
    int n0 = (b % tiles_x) * 32, k0 = (b / tiles_x) * 32;
    int tx = threadIdx.x & 31, ty = threadIdx.x >> 5;   // 32 x 8
#pragma unroll
    for (int i = 0; i < 4; i++) {
        int kk = ty + i * 8;
        tile[kk][tx] = src[(size_t)(k0 + kk) * N + n0 + tx];
    }
    __syncthreads();
#pragma unroll
    for (int i = 0; i < 4; i++) {
        int nn = ty + i * 8;
        dst[(size_t)(n0 + nn) * K + k0 + tx] = f2bf(scale * tile[tx][nn]);
    }
}

// ---------------- LayerNorm (+affine), f32 in -> bf16 out ----------------
__global__ void ln_kernel(const float* __restrict__ x, u16* __restrict__ out,
                          const float* __restrict__ gammas, const float* __restrict__ betas,
                          int gi) {
    int row = blockIdx.x;
    int t = threadIdx.x;                 // 256 threads
    const float* xr = x + (size_t)row * DIM;
    float v0 = xr[t], v1 = xr[t + 256];
    __shared__ float rs[256], rq[256];
    rs[t] = v0 + v1;
    rq[t] = v0 * v0 + v1 * v1;
    __syncthreads();
    for (int o = 128; o > 0; o >>= 1) {
        if (t < o) { rs[t] += rs[t + o]; rq[t] += rq[t + o]; }
        __syncthreads();
    }
    float mean = rs[0] / DIM;
    float var  = rq[0] / DIM - mean * mean;
    float rstd = rsqrtf(var + 1e-5f);
    float g = gammas[gi], b = betas[gi];
    out[(size_t)row * DIM + t]       = f2bf(g * ((v0 - mean) * rstd) + b);
    out[(size_t)row * DIM + t + 256] = f2bf(g * ((v1 - mean) * rstd) + b);
}

// ---------------- bf16 MFMA GEMM: C(M,N) = A(M,K) @ WT(N,K)^T ----------------
constexpr int FLAG_BF16 = 1, FLAG_GELU = 2, FLAG_SPLIT = 4, FLAG_ROPE = 8;

template<int MF>
__global__ __launch_bounds__(256) void gemm_bf16(
    const u16* __restrict__ A, const u16* __restrict__ WT,
    const float* __restrict__ bias, const float* __restrict__ resid,
    void* __restrict__ Cq, void* __restrict__ Ck, void* __restrict__ Cv,
    const float* __restrict__ ct, const float* __restrict__ st,
    int M, int N, int K, int flags)
{
    constexpr int BM = MF * 64;
    __shared__ __align__(16) u16 At[2][BM * 64];   // [buf][row][k] swizzled image
    __shared__ __align__(16) u16 Bt[2][64 * 64];   // [buf][n][k]  swizzled image
    const int t = threadIdx.x, lane = t & 63, w = t >> 6;
    const int n0 = blockIdx.x * 64, m0 = blockIdx.y * BM;
    const int l15 = lane & 15, l4 = lane >> 4;

    f32x4 acc[MF][4];
#pragma unroll
    for (int m = 0; m < MF; m++)
#pragma unroll
        for (int n = 0; n < 4; n++) acc[m][n] = (f32x4){0.f, 0.f, 0.f, 0.f};

    auto stage = [&](int buf, int k0) {
#pragma unroll
        for (int i = 0; i < MF * 2; i++) {
            int c = (w * MF * 2 + i) * 64 + lane;
            int r = c >> 3, j = (c & 7) ^ (r & 7);
            gload_lds16(A + (size_t)(m0 + r) * K + k0 + j * 8,
                        (char*)At[buf] + (w * MF * 2 + i) * 1024);
        }
#pragma unroll
        for (int i = 0; i < 2; i++) {
            int c = (w * 2 + i) * 64 + lane;
            int r = c >> 3, j = (c & 7) ^ (r & 7);
            gload_lds16(WT + (size_t)(n0 + r) * K + k0 + j * 8,
                        (char*)Bt[buf] + (w * 2 + i) * 1024);
        }
    };

    const int NT = K / 64;
    stage(0, 0);
    for (int ti = 0; ti < NT; ti++) {
        const int cur = ti & 1;
        asm volatile("s_waitcnt vmcnt(0)" ::: "memory");
        __syncthreads();
        if (ti + 1 < NT) stage(cur ^ 1, (ti + 1) * 64);
        __builtin_amdgcn_s_setprio(1);
#pragma unroll
        for (int kk = 0; kk < 2; kk++) {
            bf16x8 af[MF], bfr[4];
#pragma unroll
            for (int m = 0; m < MF; m++) {
                int row = w * MF * 16 + m * 16 + l15;
                af[m] = *(bf16x8*)((char*)At[cur] + row * 128 +
                                   ((kk * 64 + l4 * 16) ^ ((row & 7) << 4)));
            }
#pragma unroll
            for (int n = 0; n < 4; n++) {
                int row = n * 16 + l15;
                bfr[n] = *(bf16x8*)((char*)Bt[cur] + row * 128 +
                                    ((kk * 64 + l4 * 16) ^ ((row & 7) << 4)));
            }
#pragma unroll
            for (int m = 0; m < MF; m++)
#pragma unroll
                for (int n = 0; n < 4; n++)
                    acc[m][n] = __builtin_amdgcn_mfma_f32_16x16x32_bf16(
                        af[m], bfr[n], acc[m][n], 0, 0, 0);
        }
        __builtin_amdgcn_s_setprio(0);
    }

    // epilogue
    const int which = n0 >> 9;        // split: which of q/k/v
    const int nloc0 = n0 & 511;
#pragma unroll
    for (int m = 0; m < MF; m++)
#pragma unroll
        for (int rr = 0; rr < 4; rr++) {
            int row = m0 + w * MF * 16 + m * 16 + l4 * 4 + rr;
#pragma unroll
            for (int n = 0; n < 4; n++) {
                int colg = n0 + n * 16 + l15;
                float cv = acc[m][n][rr];
                if (bias) cv += bias[colg];
                // fused RoPE for q/k sections: head-col = n*16+l15 < 32 iff n < 2
                if ((flags & FLAG_ROPE) && which < 2 && n < 2) {
                    float partner = __shfl_xor(cv, 1, 64);
                    int i = (n * 16 + l15) >> 1;
                    float cc = ct[row * 16 + i], ss = st[row * 16 + i];
                    cv = (l15 & 1) ? (cv * cc + partner * ss) : (cv * cc - partner * ss);
                }
                if (flags & FLAG_GELU) cv = 0.5f * cv * (1.0f + erff(cv * 0.70710678118f));
                if (resid) cv += resid[(size_t)row * N + colg];
                if (flags & FLAG_SPLIT) {
                    u16* dst = which == 0 ? (u16*)Cq : which == 1 ? (u16*)Ck : (u16*)Cv;
                    dst[(size_t)row * 512 + nloc0 + n * 16 + l15] = f2bf(cv);
                } else if (flags & FLAG_BF16) {
                    ((u16*)Cq)[(size_t)row * N + colg] = f2bf(cv);
                } else {
                    ((float*)Cq)[(size_t)row * N + colg] = cv;
                }
            }
        }
}

// ---------------- per-head transpose: src (S, NH*HD) bf16 -> dst (NH, HD, S) bf16 ----------------
__global__ void transpose_hd(const u16* __restrict__ src, u16* __restrict__ dst) {
    __shared__ __align__(16) u16 tile[64][80];
    int h = blockIdx.y;
    int s0 = blockIdx.x * 64;
    int t = threadIdx.x;               // 256
#pragma unroll
    for (int p = 0; p < 2; p++) {
        int c = p * 256 + t;
        int r = c >> 3, j = c & 7;
        u16x8 v = *(const u16x8*)(src + (size_t)(s0 + r) * DIM + h * HDIM + j * 8);
        *(u16x8*)&tile[r][j * 8] = v;
    }
    __syncthreads();
#pragma unroll
    for (int p = 0; p < 2; p++) {
        int c = p * 256 + t;
        int d = c >> 3, j = c & 7;
        u16x8 v;
#pragma unroll
        for (int i = 0; i < 8; i++) v[i] = tile[j * 8 + i][d];
        *(u16x8*)(dst + ((size_t)h * HDIM + d) * SEQ + s0 + j * 8) = v;
    }
}

// ---------------- flash attention, 32 q/wave, KV-split x3, static-shift exp2 ----------------
// grid (NH, SEQ/128, KSPLIT), 256 threads = 4 waves, 32 q-rows/wave (2 q-halves).
// S^T = mfma(A=K, B=Q); P = exp2(S + mask2); O^T = mfma(A=V^T, B=P).
// Unnormalized partials summed in combine (static shift => no max merge).
__global__ __launch_bounds__(256, 3) void fattn_kernel(
    const u16* __restrict__ q, const u16* __restrict__ k,
    const u16* __restrict__ vT, const float* __restrict__ maskf,
    u16* __restrict__ Opart, float* __restrict__ lpart)
{
    __shared__ __align__(16) u16 k_s[2][64 * 64];     // 16 KB [buf][key][d] swizzled image
    __shared__ __align__(16) u16 vt_s[2][64 * 64];    // 16 KB [buf][d][key] swizzled image
    __shared__ __align__(16) u16 p_s[4][32 * 64];     // 16 KB per-wave [q][key] swizzled

    const int t = threadIdx.x;
    const int lane = t & 63;
    const int w = t >> 6;
    const int h = blockIdx.x;
    const int q0 = blockIdx.y * 128;
    const int split = blockIdx.z;
    const int tstart = (split == 0) ? 0 : (split == 1 ? 22 : 43);
    const int tcnt   = (split == 0) ? 22 : 21;
    const int l15 = lane & 15, g = lane >> 4;

    // Q as B-frags, straight from global: q-row = q0+w*32+qh*16+l15, d = g*8+j (+32)
    bf16x8 qf[2][2];
#pragma unroll
    for (int qh = 0; qh < 2; qh++) {
        const u16* qrow = q + (size_t)(q0 + w * 32 + qh * 16 + l15) * DIM + h * HDIM;
        qf[qh][0] = *(const bf16x8*)(qrow + g * 8);
        qf[qh][1] = *(const bf16x8*)(qrow + g * 8 + 32);
    }

    f32x4 O[2][4];                    // O^T: [qh][dt], reg r -> d = dt*16+4g+r, col q
#pragma unroll
    for (int qh = 0; qh < 2; qh++)
#pragma unroll
        for (int dt = 0; dt < 4; dt++) O[qh][dt] = (f32x4){0.f, 0.f, 0.f, 0.f};
    float lrun[2] = {0.f, 0.f};

    char* pbase = (char*)p_s[w];
    const int psw = (l15 & 7) << 4;

    auto stage = [&](int buf, int kb2) {
#pragma unroll
        for (int i = 0; i < 2; i++) {
            int c = (w * 2 + i) * 64 + lane;
            int r = c >> 3, j = (c & 7) ^ (r & 7);
            gload_lds16(k + (size_t)(kb2 + r) * DIM + h * HDIM + j * 8,
                        (char*)k_s + buf * 8192 + (w * 2 + i) * 1024);
            gload_lds16(vT + ((size_t)h * HDIM + r) * SEQ + kb2 + j * 8,
                        (char*)vt_s + buf * 8192 + (w * 2 + i) * 1024);
        }
    };

    stage(0, tstart * 64);
    for (int ti = 0; ti < tcnt; ti++) {
        const int cur = ti & 1;
        const int kb = (tstart + ti) * 64;
        asm volatile("s_waitcnt vmcnt(0)" ::: "memory");
        __syncthreads();
        if (ti + 1 < tcnt) stage(cur ^ 1, kb + 64);

        char* kcur = (char*)k_s + cur * 8192;
        char* vcur = (char*)vt_s + cur * 8192;

        // ---- QK^T (swapped): 2 independent chains (qh) off shared K A-frags ----
        f32x4 sacc[2][4];
        __builtin_amdgcn_s_setprio(1);
#pragma unroll
        for (int kt = 0; kt < 4; kt++) {
            int key = kt * 16 + l15;
            int ksw = (key & 7) << 4;
            char* kbase = kcur + key * 128;
            bf16x8 a0 = *(bf16x8*)(kbase + ((g * 16)      ^ ksw));
            bf16x8 a1 = *(bf16x8*)(kbase + ((g * 16 + 64) ^ ksw));
#pragma unroll
            for (int qh = 0; qh < 2; qh++) {
                f32x4 z = (f32x4){0.f, 0.f, 0.f, 0.f};
                z = __builtin_amdgcn_mfma_f32_16x16x32_bf16(a0, qf[qh][0], z, 0, 0, 0);
                z = __builtin_amdgcn_mfma_f32_16x16x32_bf16(a1, qf[qh][1], z, 0, 0, 0);
                sacc[qh][kt] = z;
            }
        }
        __builtin_amdgcn_s_setprio(0);

        // ---- mask (hoisted, shared across qh) + P = exp2 + lrun + b64 pack ----
        float4 mf4[4];
#pragma unroll
        for (int kt = 0; kt < 4; kt++)
            mf4[kt] = *(const float4*)(maskf + kb + kt * 16 + g * 4);
#pragma unroll
        for (int qh = 0; qh < 2; qh++)
#pragma unroll
            for (int kt = 0; kt < 4; kt++) {
                float p0 = exp2f_fast(sacc[qh][kt][0] + mf4[kt].x);
                float p1 = exp2f_fast(sacc[qh][kt][1] + mf4[kt].y);
                float p2 = exp2f_fast(sacc[qh][kt][2] + mf4[kt].z);
                float p3 = exp2f_fast(sacc[qh][kt][3] + mf4[kt].w);
                lrun[qh] += (p0 + p1) + (p2 + p3);
                uint2 pk;
                pk.x = cvtpk(p0, p1);
                pk.y = cvtpk(p2, p3);
                int colb = (kt * 16 + g * 4) * 2;          // byte col, 8B aligned
                *(uint2*)(pbase + (qh * 16 + l15) * 128 + (colb ^ psw)) = pk;
            }

        // ---- PV: O^T += V^T(A) @ P(B), V-frags shared across qh ----
        __builtin_amdgcn_s_setprio(1);
#pragma unroll
        for (int h2 = 0; h2 < 2; h2++) {
            bf16x8 pb[2];
#pragma unroll
            for (int qh = 0; qh < 2; qh++)
                pb[qh] = *(bf16x8*)(pbase + (qh * 16 + l15) * 128 +
                                    (((h2 * 4 + g) * 16) ^ psw));
#pragma unroll
            for (int dt = 0; dt < 4; dt++) {
                int d = dt * 16 + l15;
                bf16x8 va = *(bf16x8*)(vcur + d * 128 +
                                       (((h2 * 4 + g) * 16) ^ ((d & 7) << 4)));
#pragma unroll
                for (int qh = 0; qh < 2; qh++)
                    O[qh][dt] = __builtin_amdgcn_mfma_f32_16x16x32_bf16(
                        va, pb[qh], O[qh][dt], 0, 0, 0);
            }
        }
        __builtin_amdgcn_s_setprio(0);
    }

    // ---- epilogue: unnormalized partial O (bf16) + partial row sums ----
#pragma unroll
    for (int qh = 0; qh < 2; qh++) {
        lrun[qh] += __shfl_xor(lrun[qh], 16, 64);
        lrun[qh] += __shfl_xor(lrun[qh], 32, 64);
        int row = q0 + w * 32 + qh * 16 + l15;
        u16* orow = Opart + (size_t)split * SEQ * DIM + (size_t)row * DIM + h * HDIM;
#pragma unroll
        for (int dt = 0; dt < 4; dt++)
#pragma unroll
            for (int r = 0; r < 4; r += 2) {
                unsigned int pk = cvtpk(O[qh][dt][r], O[qh][dt][r + 1]);
                *(unsigned int*)(orow + dt * 16 + 4 * g + r) = pk;
            }
        if (g == 0)
            lpart[((size_t)split * NH + h) * SEQ + row] = lrun[qh];
    }
}

// ---------------- combine: out = (O0+O1+O2) / (l0+l1+l2), bf16 ----------------
__global__ void attn_combine(const u16* __restrict__ Opart, const float* __restrict__ lpart,
                             u16* __restrict__ out) {
    int row = blockIdx.x;
    int t = threadIdx.x;               // 256 threads x 2 cols
    int col = t * 2;
    int h = col >> 6;
    float l = lpart[(size_t)h * SEQ + row]
            + lpart[((size_t)NH + h) * SEQ + row]
            + lpart[((size_t)2 * NH + h) * SEQ + row];
    float inv = 1.0f / l;
    const size_t SD = (size_t)SEQ * DIM;
    unsigned int ua = *(const unsigned int*)(Opart + (size_t)row * DIM + col);
    unsigned int ub = *(const unsigned int*)(Opart + SD + (size_t)row * DIM + col);
    unsigned int uc = *(const unsigned int*)(Opart + 2 * SD + (size_t)row * DIM + col);
    float o0 = bf2f((u16)(ua & 0xffff)) + bf2f((u16)(ub & 0xffff)) + bf2f((u16)(uc & 0xffff));
    float o1 = bf2f((u16)(ua >> 16))    + bf2f((u16)(ub >> 16))    + bf2f((u16)(uc >> 16));
    *(unsigned int*)(out + (size_t)row * DIM + col) = cvtpk(o0 * inv, o1 * inv);
}

extern "C" void kernel_launch(void* const* d_in, const int* in_sizes, int n_in,
                              void* d_out, int out_size, void* d_ws, size_t ws_size,
                              hipStream_t stream) {
    const float* x      = (const float*)d_in[0];
    const float* gammas = (const float*)d_in[1];
    const float* betas  = (const float*)d_in[2];
    const float* wq     = (const float*)d_in[3];
    const float* wk     = (const float*)d_in[4];
    const float* wv     = (const float*)d_in[5];
    const float* wo     = (const float*)d_in[6];
    const float* bo     = (const float*)d_in[7];
    const float* w1     = (const float*)d_in[8];
    const float* b1     = (const float*)d_in[9];
    const float* w2     = (const float*)d_in[10];
    const float* b2     = (const float*)d_in[11];
    const int*   mask   = (const int*)d_in[12];
    float* out = (float*)d_out;

    // ---- workspace layout (bytes); peak use < 40 MB ----
    char* wsb = (char*)d_ws;
    u16*   h1b   = (u16*)(wsb + 0);                 // 4 MB; LN1 out; attnb; f1b start
    u16*   kb    = (u16*)(wsb + (4ull  << 20));     // 4 MB
    u16*   vb    = (u16*)(wsb + (8ull  << 20));     // 4 MB; dead after transpose -> lpart
    u16*   vTb   = (u16*)(wsb + (12ull << 20));     // 4 MB
    u16*   qb    = (u16*)(wsb + (16ull << 20));     // 4 MB; reused as h2b
    float* x2    = (float*)(wsb + (20ull << 20));   // 8 MB (written after Opart consumed)
    u16*   Opart = (u16*)(wsb + (20ull << 20));     // 12 MB: 3 splits x 4 MB (20-32)
    u16*   wqkvT = (u16*)(wsb + (32ull << 20));     // 1.5 MB
    u16*   woT   = wqkvT + 1536 * 512;              // 0.5 MB
    u16*   w1T   = woT   + 512 * 512;               // 2 MB
    u16*   w2T   = w1T   + 2048 * 512;              // 2 MB
    float* maskf = (float*)(wsb + (38ull << 20));   // 16 KB
    float* ct    = (float*)(wsb + (39ull << 20));   // 256 KB
    float* st    = ct + 65536;                      // 256 KB
    float* lpart = (float*)vb;                      // 384 KB in dead vb region
    u16*   f1b   = h1b;                             // 16 MB spanning slots 0-3 (FFN phase)
    u16*   h2b   = qb;
    u16*   attnb = h1b;

    // 0. fused prep: mask + rope tables + weight converts (1 dispatch)
    prep_kernel<<<16 + 256 + 3072, 256, 0, stream>>>(wq, wk, wv, wo, w1, w2,
                                                     wqkvT, woT, w1T, w2T,
                                                     mask, maskf, ct, st);
    // 1. h1 = LN(x) (bf16)
    ln_kernel<<<SEQ, 256, 0, stream>>>(x, h1b, gammas, betas, 0);
    // 2. fused QKV projection + RoPE in epilogue (q pre-scaled by log2e/8)
    gemm_bf16<2><<<dim3(1536 / 64, SEQ / 128), 256, 0, stream>>>(
        h1b, wqkvT, nullptr, nullptr, qb, kb, vb, ct, st,
        SEQ, 1536, DIM, FLAG_SPLIT | FLAG_BF16 | FLAG_ROPE);
    // 3. vT = per-head transpose of v
    transpose_hd<<<dim3(SEQ / 64, NH), 256, 0, stream>>>(vb, vTb);
    // 4. attention, KV-split x3 (partials), then combine
    fattn_kernel<<<dim3(NH, SEQ / 128, KSPLIT), 256, 0, stream>>>(
        qb, kb, vTb, maskf, Opart, lpart);
    attn_combine<<<SEQ, 256, 0, stream>>>(Opart, lpart, attnb);
    // 5. x2 = x + attn@wo + bo (f32)
    gemm_bf16<1><<<dim3(DIM / 64, SEQ / 64), 256, 0, stream>>>(
        attnb, woT, bo, x, x2, nullptr, nullptr, nullptr, nullptr, SEQ, DIM, DIM, 0);
    // 6. h2 = LN(x2) (bf16)
    ln_kernel<<<SEQ, 256, 0, stream>>>(x2, h2b, gammas, betas, 1);
    // 7. f1 = gelu(h2@w1 + b1) (bf16)
    gemm_bf16<2><<<dim3(FFD / 64, SEQ / 128), 256, 0, stream>>>(
        h2b, w1T, b1, nullptr, f1b, nullptr, nullptr, nullptr, nullptr,
        SEQ, FFD, DIM, FLAG_BF16 | FLAG_GELU);
    // 8. out = x2 + f1@w2 + b2 (f32)
    gemm_bf16<1><<<dim3(DIM / 64, SEQ / 64), 256, 0, stream>>>(
        f1b, w2T, b2, x2, out, nullptr, nullptr, nullptr, nullptr, SEQ, DIM, FFD, 0);
}